// Round 1
// baseline (8778.983 us; speedup 1.0000x reference)
//
#include <hip/hip_runtime.h>
#include <hip/hip_bf16.h>
#include <math.h>

// Problem constants
#define CB 8        // batch
#define CN 2048     // seq len
#define CD 768      // dim
#define CDQKV 2304  // 3*dim
#define NG 49       // groups

__device__ __forceinline__ float sigmoidf_(float x) { return 1.f / (1.f + __expf(-x)); }

// -------------------------------------------------------------------------
// marker kernel: workspace too small -> make the failure loudly diagnosable
// -------------------------------------------------------------------------
__global__ void ws_fail_marker(float* out) {
    if (threadIdx.x == 0 && blockIdx.x == 0) out[0] = 31337.0f;
}

// -------------------------------------------------------------------------
// K1: qkv = x @ W_qkv + b_qkv, split-written into q,k,v  [16384 x 2304]
// 128x128 tile, BK=16, 256 threads, 8x8 micro-tile
// -------------------------------------------------------------------------
__global__ __launch_bounds__(256, 2) void qkv_gemm(
    const float* __restrict__ X, const float* __restrict__ W, const float* __restrict__ bias,
    float* __restrict__ Q, float* __restrict__ K, float* __restrict__ V)
{
    __shared__ float As[16][132];
    __shared__ float Bs[16][132];
    const int tid = threadIdx.x;
    const int tx = tid & 15, ty = tid >> 4;
    const int m0 = blockIdx.x * 128;
    const int c0 = blockIdx.y * 128;

    float accu[8][8];
#pragma unroll
    for (int i = 0; i < 8; i++)
#pragma unroll
        for (int j = 0; j < 8; j++) accu[i][j] = 0.f;

    for (int kt = 0; kt < CD / 16; ++kt) {
        __syncthreads();
        {   // A: 128 rows x 16 k, transposed store As[k][m]
            int r = tid >> 1;
            int cb = (tid & 1) * 8;
            const float* src = X + (size_t)(m0 + r) * CD + kt * 16 + cb;
            float4 v0 = *(const float4*)(src);
            float4 v1 = *(const float4*)(src + 4);
            As[cb + 0][r] = v0.x; As[cb + 1][r] = v0.y; As[cb + 2][r] = v0.z; As[cb + 3][r] = v0.w;
            As[cb + 4][r] = v1.x; As[cb + 5][r] = v1.y; As[cb + 6][r] = v1.z; As[cb + 7][r] = v1.w;
        }
        {   // B: 16 k x 128 cols
            int f = tid * 4;
            int r = f >> 7, c = f & 127;
            *(float4*)&Bs[r][c] = *(const float4*)(W + (size_t)(kt * 16 + r) * CDQKV + c0 + c);
            int f1 = f + 1024;
            int r1 = f1 >> 7, c1 = f1 & 127;
            *(float4*)&Bs[r1][c1] = *(const float4*)(W + (size_t)(kt * 16 + r1) * CDQKV + c0 + c1);
        }
        __syncthreads();
#pragma unroll
        for (int kk = 0; kk < 16; kk++) {
            float a[8], b[8];
#pragma unroll
            for (int i = 0; i < 8; i++) a[i] = As[kk][ty + 16 * i];
#pragma unroll
            for (int j = 0; j < 8; j++) b[j] = Bs[kk][tx + 16 * j];
#pragma unroll
            for (int i = 0; i < 8; i++)
#pragma unroll
                for (int j = 0; j < 8; j++) accu[i][j] = fmaf(a[i], b[j], accu[i][j]);
        }
    }
    // split-write: the 128-col block lies entirely in one of q/k/v (768 = 6*128)
    const int seg = c0 / CD;
    const int cb0 = c0 % CD;
    float* dst = (seg == 0) ? Q : (seg == 1) ? K : V;
#pragma unroll
    for (int j = 0; j < 8; j++) {
        int cc = cb0 + tx + 16 * j;
        float bv = bias[c0 + tx + 16 * j];
#pragma unroll
        for (int i = 0; i < 8; i++) {
            int m = m0 + ty + 16 * i;
            dst[(size_t)m * CD + cc] = accu[i][j] + bv;
        }
    }
}

// -------------------------------------------------------------------------
// K5: out = op @ W_proj + b_proj   [16384 x 768]
// -------------------------------------------------------------------------
__global__ __launch_bounds__(256, 2) void proj_gemm(
    const float* __restrict__ X, const float* __restrict__ W, const float* __restrict__ bias,
    float* __restrict__ OUT)
{
    __shared__ float As[16][132];
    __shared__ float Bs[16][132];
    const int tid = threadIdx.x;
    const int tx = tid & 15, ty = tid >> 4;
    const int m0 = blockIdx.x * 128;
    const int c0 = blockIdx.y * 128;

    float accu[8][8];
#pragma unroll
    for (int i = 0; i < 8; i++)
#pragma unroll
        for (int j = 0; j < 8; j++) accu[i][j] = 0.f;

    for (int kt = 0; kt < CD / 16; ++kt) {
        __syncthreads();
        {
            int r = tid >> 1;
            int cb = (tid & 1) * 8;
            const float* src = X + (size_t)(m0 + r) * CD + kt * 16 + cb;
            float4 v0 = *(const float4*)(src);
            float4 v1 = *(const float4*)(src + 4);
            As[cb + 0][r] = v0.x; As[cb + 1][r] = v0.y; As[cb + 2][r] = v0.z; As[cb + 3][r] = v0.w;
            As[cb + 4][r] = v1.x; As[cb + 5][r] = v1.y; As[cb + 6][r] = v1.z; As[cb + 7][r] = v1.w;
        }
        {
            int f = tid * 4;
            int r = f >> 7, c = f & 127;
            *(float4*)&Bs[r][c] = *(const float4*)(W + (size_t)(kt * 16 + r) * CD + c0 + c);
            int f1 = f + 1024;
            int r1 = f1 >> 7, c1 = f1 & 127;
            *(float4*)&Bs[r1][c1] = *(const float4*)(W + (size_t)(kt * 16 + r1) * CD + c0 + c1);
        }
        __syncthreads();
#pragma unroll
        for (int kk = 0; kk < 16; kk++) {
            float a[8], b[8];
#pragma unroll
            for (int i = 0; i < 8; i++) a[i] = As[kk][ty + 16 * i];
#pragma unroll
            for (int j = 0; j < 8; j++) b[j] = Bs[kk][tx + 16 * j];
#pragma unroll
            for (int i = 0; i < 8; i++)
#pragma unroll
                for (int j = 0; j < 8; j++) accu[i][j] = fmaf(a[i], b[j], accu[i][j]);
        }
    }
#pragma unroll
    for (int j = 0; j < 8; j++) {
        int c = c0 + tx + 16 * j;
        float bv = bias[c];
#pragma unroll
        for (int i = 0; i < 8; i++) {
            int m = m0 + ty + 16 * i;
            OUT[(size_t)m * CD + c] = accu[i][j] + bv;
        }
    }
}

// -------------------------------------------------------------------------
// K2: gw = softmax(gelu_exact(v @ W_gp), axis=-1)   [16384 x 49]
// one wave per row
// -------------------------------------------------------------------------
__global__ void group_weights(const float* __restrict__ V, const float* __restrict__ Wg,
                              float* __restrict__ GW)
{
    __shared__ float vrow[4][CD];
    const int wid = threadIdx.x >> 6;
    const int lane = threadIdx.x & 63;
    const int row = blockIdx.x * 4 + wid;
    const float* vsrc = V + (size_t)row * CD;
    for (int i = lane * 4; i < CD; i += 64 * 4)
        *(float4*)&vrow[wid][i] = *(const float4*)(vsrc + i);
    __syncthreads();

    float dot = 0.f;
    if (lane < NG) {
        for (int k = 0; k < CD; k++) dot = fmaf(vrow[wid][k], Wg[k * NG + lane], dot);
    }
    // exact gelu: x * 0.5 * (1 + erf(x/sqrt(2)))
    float g = (lane < NG) ? 0.5f * dot * (1.f + erff(dot * 0.7071067811865475f)) : -1e30f;
    float mx = g;
#pragma unroll
    for (int s = 32; s > 0; s >>= 1) mx = fmaxf(mx, __shfl_xor(mx, s, 64));
    float e = (lane < NG) ? __expf(g - mx) : 0.f;
    float sum = e;
#pragma unroll
    for (int s = 32; s > 0; s >>= 1) sum += __shfl_xor(sum, s, 64);
    if (lane < NG) GW[(size_t)row * NG + lane] = e / sum;
}

// -------------------------------------------------------------------------
// K3: Z[b][g][d] = sum_n gw[b][n][g] * v[b][n][d]   (rank-49 factor of G@v)
// -------------------------------------------------------------------------
__global__ void z_accum(const float* __restrict__ V, const float* __restrict__ GW,
                        float* __restrict__ Z)
{
    const int b = blockIdx.x;
    const int d = blockIdx.y * 256 + threadIdx.x;
    const int n0 = blockIdx.z * 128;
    float acc[NG];
#pragma unroll
    for (int g = 0; g < NG; g++) acc[g] = 0.f;
    const float* vb = V + (size_t)b * CN * CD;
    const float* gwb = GW + (size_t)b * CN * NG;
    for (int n = n0; n < n0 + 128; ++n) {
        float vd = vb[(size_t)n * CD + d];
        const float* gr = gwb + (size_t)n * NG;
#pragma unroll
        for (int g = 0; g < NG; g++) acc[g] = fmaf(gr[g], vd, acc[g]);
    }
    float* zb = Z + (size_t)b * NG * CD;
    for (int g = 0; g < NG; g++) atomicAdd(&zb[(size_t)g * CD + d], acc[g]);
}

// -------------------------------------------------------------------------
// K4: fused flash attention with per-element group multiplier.
// block = 256 threads = 4 waves; 32 q-rows per block; k-tiles of 32.
// thread t: row sr=t/8, S-cols sm4=(t%8)*4, out-cols c = vc*128 + (t%8) + 8*i2
// logits z = (q.k)*scale*G ; online softmax; epilogue adds a*gw@Z and /l.
// -------------------------------------------------------------------------
__global__ __launch_bounds__(256, 2) void flash_kernel(
    const float* __restrict__ Q, const float* __restrict__ K, const float* __restrict__ V,
    const float* __restrict__ GW, const float* __restrict__ Z,
    const float* __restrict__ alpha_p, float* __restrict__ OP)
{
    __shared__ float Qs[32][68];
    __shared__ float Ks[32][68];
    __shared__ float Vs[32][132];
    __shared__ float Ps[32][33];
    __shared__ float gwq[32 * NG];
    __shared__ float gwk[32 * NG];

    const int tid = threadIdx.x;
    const int b = blockIdx.y;
    const int n0 = blockIdx.x * 32;
    const int sr = tid >> 3;
    const int cg = tid & 7;
    const int sm4 = cg * 4;
    const int ldoff = cg * 8;

    const float* Qb = Q + (size_t)b * CN * CD;
    const float* Kb = K + (size_t)b * CN * CD;
    const float* Vb = V + (size_t)b * CN * CD;
    const float* GWb = GW + (size_t)b * CN * NG;

    for (int i = tid; i < 32 * NG; i += 256) gwq[i] = GWb[(size_t)n0 * NG + i];

    float acc[96];
#pragma unroll
    for (int i = 0; i < 96; i++) acc[i] = 0.f;
    float mrow = -1e30f, lrow = 0.f;
    const float scale = 0.03608439182435161f;  // 768^-0.5

    for (int mt = 0; mt < CN / 32; ++mt) {
        const int km0 = mt * 32;
        float s[4] = {0.f, 0.f, 0.f, 0.f};
        // ---- S = Q.K^T over 768, chunked by 64 ----
        for (int kc = 0; kc < CD / 64; ++kc) {
            __syncthreads();
            if (kc == 0) {
                for (int i = tid; i < 32 * NG; i += 256) gwk[i] = GWb[(size_t)km0 * NG + i];
            }
            {
                const float* qsrc = Qb + (size_t)(n0 + sr) * CD + kc * 64 + ldoff;
                *(float4*)&Qs[sr][ldoff] = *(const float4*)qsrc;
                *(float4*)&Qs[sr][ldoff + 4] = *(const float4*)(qsrc + 4);
                const float* ksrc = Kb + (size_t)(km0 + sr) * CD + kc * 64 + ldoff;
                *(float4*)&Ks[sr][ldoff] = *(const float4*)ksrc;
                *(float4*)&Ks[sr][ldoff + 4] = *(const float4*)(ksrc + 4);
            }
            __syncthreads();
#pragma unroll
            for (int k4 = 0; k4 < 16; ++k4) {
                float4 qv = *(const float4*)&Qs[sr][k4 * 4];
#pragma unroll
                for (int j = 0; j < 4; j++) {
                    float4 kv = *(const float4*)&Ks[sm4 + j][k4 * 4];
                    s[j] = fmaf(qv.x, kv.x, s[j]);
                    s[j] = fmaf(qv.y, kv.y, s[j]);
                    s[j] = fmaf(qv.z, kv.z, s[j]);
                    s[j] = fmaf(qv.w, kv.w, s[j]);
                }
            }
        }
        // ---- group affinity + online softmax ----
        float z[4];
#pragma unroll
        for (int j = 0; j < 4; j++) {
            float gaff = 0.f;
            const float* gq = &gwq[sr * NG];
            const float* gk = &gwk[(sm4 + j) * NG];
            for (int g = 0; g < NG; g++) gaff = fmaf(gq[g], gk[g], gaff);
            z[j] = s[j] * scale * gaff;
        }
        float tmax = fmaxf(fmaxf(z[0], z[1]), fmaxf(z[2], z[3]));
        tmax = fmaxf(tmax, __shfl_xor(tmax, 1, 64));
        tmax = fmaxf(tmax, __shfl_xor(tmax, 2, 64));
        tmax = fmaxf(tmax, __shfl_xor(tmax, 4, 64));
        float mnew = fmaxf(mrow, tmax);
        float f = __expf(mrow - mnew);
        float p[4];
        float psum = 0.f;
#pragma unroll
        for (int j = 0; j < 4; j++) { p[j] = __expf(z[j] - mnew); psum += p[j]; }
        psum += __shfl_xor(psum, 1, 64);
        psum += __shfl_xor(psum, 2, 64);
        psum += __shfl_xor(psum, 4, 64);
        lrow = lrow * f + psum;
        mrow = mnew;
#pragma unroll
        for (int i = 0; i < 96; i++) acc[i] *= f;
#pragma unroll
        for (int j = 0; j < 4; j++) Ps[sr][sm4 + j] = p[j];
        // ---- P @ V, 6 column chunks of 128 ----
#pragma unroll
        for (int vc = 0; vc < 6; ++vc) {
            __syncthreads();
            {
                const float* vsrc = Vb + (size_t)(km0 + sr) * CD + vc * 128 + cg * 16;
                float4 a0 = *(const float4*)(vsrc);
                float4 a1 = *(const float4*)(vsrc + 4);
                float4 a2 = *(const float4*)(vsrc + 8);
                float4 a3 = *(const float4*)(vsrc + 12);
                float* dp = &Vs[sr][cg * 16];
                *(float4*)(dp) = a0; *(float4*)(dp + 4) = a1;
                *(float4*)(dp + 8) = a2; *(float4*)(dp + 12) = a3;
            }
            __syncthreads();
            for (int m = 0; m < 32; m++) {
                float pv = Ps[sr][m];
#pragma unroll
                for (int i2 = 0; i2 < 16; i2++) {
                    acc[vc * 16 + i2] = fmaf(pv, Vs[m][cg + 8 * i2], acc[vc * 16 + i2]);
                }
            }
        }
    }
    // ---- epilogue: (1-a)*acc/l + a * gw @ Z ----
    float a = sigmoidf_(alpha_p[0]);
    float inv_l = 1.f / lrow;
    const float* Zb = Z + (size_t)b * NG * CD;
    float* opb = OP + (size_t)((size_t)b * CN + n0 + sr) * CD;
#pragma unroll
    for (int vc = 0; vc < 6; vc++) {
#pragma unroll
        for (int i2 = 0; i2 < 16; i2++) {
            int c = vc * 128 + cg + 8 * i2;
            float gpart = 0.f;
            for (int g = 0; g < NG; g++) gpart = fmaf(gwq[sr * NG + g], Zb[(size_t)g * CD + c], gpart);
            opb[c] = (1.f - a) * acc[vc * 16 + i2] * inv_l + a * gpart;
        }
    }
}

// -------------------------------------------------------------------------
extern "C" void kernel_launch(void* const* d_in, const int* in_sizes, int n_in,
                              void* d_out, int out_size, void* d_ws, size_t ws_size,
                              hipStream_t stream) {
    const float* x      = (const float*)d_in[0];
    const float* W_qkv  = (const float*)d_in[1];
    const float* b_qkv  = (const float*)d_in[2];
    const float* W_proj = (const float*)d_in[3];
    const float* b_proj = (const float*)d_in[4];
    const float* W_gp   = (const float*)d_in[5];
    const float* alpha  = (const float*)d_in[6];
    float* out = (float*)d_out;

    const size_t BND = (size_t)CB * CN * CD;      // 12,582,912
    const size_t BNG = (size_t)CB * CN * NG;      // 802,816
    const size_t BGD = (size_t)CB * NG * CD;      // 301,056
    const size_t need = (4 * BND + BNG + BGD) * sizeof(float);  // ~196 MiB
    if (ws_size < need) {
        ws_fail_marker<<<1, 1, 0, stream>>>(out);
        return;
    }
    float* q  = (float*)d_ws;
    float* k  = q + BND;
    float* v  = k + BND;
    float* gw = v + BND;
    float* Zb = gw + BNG;
    float* op = Zb + BGD;

    hipMemsetAsync(Zb, 0, BGD * sizeof(float), stream);
    qkv_gemm<<<dim3(128, 18), 256, 0, stream>>>(x, W_qkv, b_qkv, q, k, v);
    group_weights<<<dim3(4096), 256, 0, stream>>>(v, W_gp, gw);
    z_accum<<<dim3(8, 3, 16), 256, 0, stream>>>(v, gw, Zb);
    flash_kernel<<<dim3(64, 8), 256, 0, stream>>>(q, k, v, gw, Zb, alpha, op);
    proj_gemm<<<dim3(128, 6), 256, 0, stream>>>(op, W_proj, b_proj, out);
}

// Round 2
// 1503.394 us; speedup vs baseline: 5.8394x; 5.8394x over previous
//
#include <hip/hip_runtime.h>
#include <hip/hip_bf16.h>
#include <math.h>

// Problem constants
#define CB 8        // batch
#define CN 2048     // seq len
#define CD 768      // dim
#define CDQKV 2304  // 3*dim
#define NG 49       // groups

typedef unsigned short ushort_t;
typedef __attribute__((ext_vector_type(8))) short bf16x8;
typedef __attribute__((ext_vector_type(4))) float f32x4;

__device__ __forceinline__ float bf2f(ushort_t u) {
    unsigned int x = ((unsigned int)u) << 16;
    return __builtin_bit_cast(float, x);
}
__device__ __forceinline__ ushort_t f2bf(float f) {
    unsigned int u = __builtin_bit_cast(unsigned int, f);
    u += 0x7fff + ((u >> 16) & 1);   // RNE
    return (ushort_t)(u >> 16);
}
__device__ __forceinline__ float sigmoidf_(float x) { return 1.f / (1.f + __expf(-x)); }

// -------------------------------------------------------------------------
__global__ void ws_fail_marker(float* out) {
    if (threadIdx.x == 0 && blockIdx.x == 0) out[0] = 31337.0f;
}

// -------------------------------------------------------------------------
// K1: qkv = x @ W_qkv + b_qkv -> bf16 q,k,v   (fp32 compute, unchanged core)
// -------------------------------------------------------------------------
__global__ __launch_bounds__(256, 2) void qkv_gemm(
    const float* __restrict__ X, const float* __restrict__ W, const float* __restrict__ bias,
    ushort_t* __restrict__ Q, ushort_t* __restrict__ K, ushort_t* __restrict__ V)
{
    __shared__ float As[16][132];
    __shared__ float Bs[16][132];
    const int tid = threadIdx.x;
    const int tx = tid & 15, ty = tid >> 4;
    const int m0 = blockIdx.x * 128;
    const int c0 = blockIdx.y * 128;

    float accu[8][8];
#pragma unroll
    for (int i = 0; i < 8; i++)
#pragma unroll
        for (int j = 0; j < 8; j++) accu[i][j] = 0.f;

    for (int kt = 0; kt < CD / 16; ++kt) {
        __syncthreads();
        {
            int r = tid >> 1;
            int cb = (tid & 1) * 8;
            const float* src = X + (size_t)(m0 + r) * CD + kt * 16 + cb;
            float4 v0 = *(const float4*)(src);
            float4 v1 = *(const float4*)(src + 4);
            As[cb + 0][r] = v0.x; As[cb + 1][r] = v0.y; As[cb + 2][r] = v0.z; As[cb + 3][r] = v0.w;
            As[cb + 4][r] = v1.x; As[cb + 5][r] = v1.y; As[cb + 6][r] = v1.z; As[cb + 7][r] = v1.w;
        }
        {
            int f = tid * 4;
            int r = f >> 7, c = f & 127;
            *(float4*)&Bs[r][c] = *(const float4*)(W + (size_t)(kt * 16 + r) * CDQKV + c0 + c);
            int f1 = f + 1024;
            int r1 = f1 >> 7, c1 = f1 & 127;
            *(float4*)&Bs[r1][c1] = *(const float4*)(W + (size_t)(kt * 16 + r1) * CDQKV + c0 + c1);
        }
        __syncthreads();
#pragma unroll
        for (int kk = 0; kk < 16; kk++) {
            float a[8], b[8];
#pragma unroll
            for (int i = 0; i < 8; i++) a[i] = As[kk][ty + 16 * i];
#pragma unroll
            for (int j = 0; j < 8; j++) b[j] = Bs[kk][tx + 16 * j];
#pragma unroll
            for (int i = 0; i < 8; i++)
#pragma unroll
                for (int j = 0; j < 8; j++) accu[i][j] = fmaf(a[i], b[j], accu[i][j]);
        }
    }
    const int seg = c0 / CD;
    const int cb0 = c0 % CD;
    ushort_t* dst = (seg == 0) ? Q : (seg == 1) ? K : V;
#pragma unroll
    for (int j = 0; j < 8; j++) {
        int cc = cb0 + tx + 16 * j;
        float bv = bias[c0 + tx + 16 * j];
#pragma unroll
        for (int i = 0; i < 8; i++) {
            int m = m0 + ty + 16 * i;
            dst[(size_t)m * CD + cc] = f2bf(accu[i][j] + bv);
        }
    }
}

// -------------------------------------------------------------------------
// K5: out = op @ W_proj + b_proj (fp32, unchanged)
// -------------------------------------------------------------------------
__global__ __launch_bounds__(256, 2) void proj_gemm(
    const float* __restrict__ X, const float* __restrict__ W, const float* __restrict__ bias,
    float* __restrict__ OUT)
{
    __shared__ float As[16][132];
    __shared__ float Bs[16][132];
    const int tid = threadIdx.x;
    const int tx = tid & 15, ty = tid >> 4;
    const int m0 = blockIdx.x * 128;
    const int c0 = blockIdx.y * 128;

    float accu[8][8];
#pragma unroll
    for (int i = 0; i < 8; i++)
#pragma unroll
        for (int j = 0; j < 8; j++) accu[i][j] = 0.f;

    for (int kt = 0; kt < CD / 16; ++kt) {
        __syncthreads();
        {
            int r = tid >> 1;
            int cb = (tid & 1) * 8;
            const float* src = X + (size_t)(m0 + r) * CD + kt * 16 + cb;
            float4 v0 = *(const float4*)(src);
            float4 v1 = *(const float4*)(src + 4);
            As[cb + 0][r] = v0.x; As[cb + 1][r] = v0.y; As[cb + 2][r] = v0.z; As[cb + 3][r] = v0.w;
            As[cb + 4][r] = v1.x; As[cb + 5][r] = v1.y; As[cb + 6][r] = v1.z; As[cb + 7][r] = v1.w;
        }
        {
            int f = tid * 4;
            int r = f >> 7, c = f & 127;
            *(float4*)&Bs[r][c] = *(const float4*)(W + (size_t)(kt * 16 + r) * CD + c0 + c);
            int f1 = f + 1024;
            int r1 = f1 >> 7, c1 = f1 & 127;
            *(float4*)&Bs[r1][c1] = *(const float4*)(W + (size_t)(kt * 16 + r1) * CD + c0 + c1);
        }
        __syncthreads();
#pragma unroll
        for (int kk = 0; kk < 16; kk++) {
            float a[8], b[8];
#pragma unroll
            for (int i = 0; i < 8; i++) a[i] = As[kk][ty + 16 * i];
#pragma unroll
            for (int j = 0; j < 8; j++) b[j] = Bs[kk][tx + 16 * j];
#pragma unroll
            for (int i = 0; i < 8; i++)
#pragma unroll
                for (int j = 0; j < 8; j++) accu[i][j] = fmaf(a[i], b[j], accu[i][j]);
        }
    }
#pragma unroll
    for (int j = 0; j < 8; j++) {
        int c = c0 + tx + 16 * j;
        float bv = bias[c];
#pragma unroll
        for (int i = 0; i < 8; i++) {
            int m = m0 + ty + 16 * i;
            OUT[(size_t)m * CD + c] = accu[i][j] + bv;
        }
    }
}

// -------------------------------------------------------------------------
// K2: gw = softmax(gelu_exact(v @ W_gp)); writes fp32 gw + zero-padded bf16 gwp[.][64]
// -------------------------------------------------------------------------
__global__ void group_weights(const ushort_t* __restrict__ V, const float* __restrict__ Wg,
                              float* __restrict__ GW, ushort_t* __restrict__ GWP)
{
    __shared__ float vrow[4][CD];
    const int wid = threadIdx.x >> 6;
    const int lane = threadIdx.x & 63;
    const int row = blockIdx.x * 4 + wid;
    const ushort_t* vsrc = V + (size_t)row * CD;
    for (int i = lane * 4; i < CD; i += 256) {
        uint2 u = *(const uint2*)(vsrc + i);
        vrow[wid][i + 0] = bf2f((ushort_t)(u.x & 0xffff));
        vrow[wid][i + 1] = bf2f((ushort_t)(u.x >> 16));
        vrow[wid][i + 2] = bf2f((ushort_t)(u.y & 0xffff));
        vrow[wid][i + 3] = bf2f((ushort_t)(u.y >> 16));
    }
    __syncthreads();

    float dot = 0.f;
    if (lane < NG) {
        for (int k = 0; k < CD; k++) dot = fmaf(vrow[wid][k], Wg[k * NG + lane], dot);
    }
    float gl = (lane < NG) ? 0.5f * dot * (1.f + erff(dot * 0.7071067811865475f)) : -1e30f;
    float mx = gl;
#pragma unroll
    for (int s = 32; s > 0; s >>= 1) mx = fmaxf(mx, __shfl_xor(mx, s, 64));
    float e = (lane < NG) ? __expf(gl - mx) : 0.f;
    float sum = e;
#pragma unroll
    for (int s = 32; s > 0; s >>= 1) sum += __shfl_xor(sum, s, 64);
    float wv = e / sum;
    if (lane < NG) GW[(size_t)row * NG + lane] = wv;
    GWP[(size_t)row * 64 + lane] = (lane < NG) ? f2bf(wv) : (ushort_t)0;
}

// -------------------------------------------------------------------------
// K3: Z[b][g][d] = sum_n gw[b][n][g] * v[b][n][d]
// -------------------------------------------------------------------------
__global__ void z_accum(const ushort_t* __restrict__ V, const float* __restrict__ GW,
                        float* __restrict__ Z)
{
    const int b = blockIdx.x;
    const int d = blockIdx.y * 256 + threadIdx.x;
    const int n0 = blockIdx.z * 128;
    float acc[NG];
#pragma unroll
    for (int g = 0; g < NG; g++) acc[g] = 0.f;
    const ushort_t* vb = V + (size_t)b * CN * CD;
    const float* gwb = GW + (size_t)b * CN * NG;
    for (int n = n0; n < n0 + 128; ++n) {
        float vd = bf2f(vb[(size_t)n * CD + d]);
        const float* gr = gwb + (size_t)n * NG;
#pragma unroll
        for (int g = 0; g < NG; g++) acc[g] = fmaf(gr[g], vd, acc[g]);
    }
    float* zb = Z + (size_t)b * NG * CD;
    for (int g = 0; g < NG; g++) atomicAdd(&zb[(size_t)g * CD + d], acc[g]);
}

// -------------------------------------------------------------------------
// K3b: GZ[n][d] = sum_g gw[n][g] * Z[b][g][d]   (bf16 out)
// grid (nchunk=16, dchunk=3, b=8), 256 thr
// -------------------------------------------------------------------------
__global__ __launch_bounds__(256) void gz_kernel(const float* __restrict__ GWf,
                                                 const float* __restrict__ Z,
                                                 ushort_t* __restrict__ GZ)
{
    __shared__ float Zs[NG][256];
    const int nb = blockIdx.x, dc = blockIdx.y, b = blockIdx.z;
    const int tid = threadIdx.x;
    const float* Zb = Z + (size_t)b * NG * CD + dc * 256;
    for (int idx = tid; idx < NG * 256; idx += 256) {
        int gg = idx >> 8, dd = idx & 255;
        Zs[gg][dd] = Zb[(size_t)gg * CD + dd];
    }
    __syncthreads();
    const int n0 = b * CN + nb * 128;
    for (int n = 0; n < 128; n++) {
        const float* gr = GWf + (size_t)(n0 + n) * NG;
        float a = 0.f;
#pragma unroll
        for (int gg = 0; gg < NG; gg++) a = fmaf(gr[gg], Zs[gg][tid], a);
        GZ[(size_t)(n0 + n) * CD + dc * 256 + tid] = f2bf(a);
    }
}

// -------------------------------------------------------------------------
// K3c: vt[b][d][n] = v[b][n][d]  (bf16 transpose), 64x64 tiles
// -------------------------------------------------------------------------
__global__ __launch_bounds__(256) void vt_transpose(const ushort_t* __restrict__ VB,
                                                    ushort_t* __restrict__ VT)
{
    __shared__ ushort_t tile[64][72];
    const int bx = blockIdx.x, by = blockIdx.y, b = blockIdx.z;
    const int t = threadIdx.x;
    const int r = t >> 2, cp = (t & 3) * 16;
    const ushort_t* src = VB + ((size_t)b * CN + bx * 64 + r) * CD + by * 64 + cp;
    *(uint4*)&tile[r][cp] = *(const uint4*)src;
    *(uint4*)&tile[r][cp + 8] = *(const uint4*)(src + 8);
    __syncthreads();
    ushort_t tmp[16];
#pragma unroll
    for (int i = 0; i < 16; i++) tmp[i] = tile[cp + i][r];
    ushort_t* dst = VT + ((size_t)b * CD + by * 64 + r) * CN + bx * 64 + cp;
    *(uint4*)dst = *(uint4*)tmp;
    *(uint4*)(dst + 8) = *(uint4*)(tmp + 8);
}

// -------------------------------------------------------------------------
// K4: MFMA flash attention with group multiplier.
// 512 thr = 8 waves; 64 q-rows/block; KV tiles of 128; d chunks of 64.
// S-partition: wave w -> qcol=w&3 (16q), kvh=w>>2 (64kv).  (S^T = K.Q^T MFMA)
// PV-partition: wave w -> qh=w&1 (32q), dgrp=w>>1 (chunks dc2%4==dgrp).
// -------------------------------------------------------------------------
#define STAGE_K(buf_, kvb_, dc_) do {                                              \
    const ushort_t* _src = Kg + (size_t)((kvb_) + st_r4) * CD + (dc_) * 64;        \
    _Pragma("unroll")                                                              \
    for (int _u = 0; _u < 2; _u++) {                                               \
        int _slot = st_p4 * 2 + _u;                                                \
        int _phys = _slot ^ (st_r4 & 7);                                           \
        *(uint4*)((buf_) + st_r4 * 128 + _phys * 16) = *(const uint4*)(_src + _slot * 8); \
    } } while (0)

#define STAGE_V(buf_, kvb_, dc2_) do {                                             \
    const ushort_t* _src = Vg + (size_t)((dc2_) * 64 + st_r8) * CN + (kvb_);       \
    _Pragma("unroll")                                                              \
    for (int _u = 0; _u < 2; _u++) {                                               \
        int _slot = st_p8 * 2 + _u;                                                \
        int _phys = (_slot & 8) | ((_slot & 7) ^ (st_r8 & 7));                     \
        *(uint4*)((buf_) + st_r8 * 256 + _phys * 16) = *(const uint4*)(_src + _slot * 8); \
    } } while (0)

#define STAGE_GWK(kvb_) do {                                                       \
    const ushort_t* _src = Gg + (size_t)((kvb_) + st_r4) * 64 + st_p4 * 16;        \
    ushort_t* _dst = (ushort_t*)gwkP + st_r4 * 72 + st_p4 * 16;                    \
    *(uint4*)(_dst) = *(const uint4*)(_src);                                       \
    *(uint4*)(_dst + 8) = *(const uint4*)(_src + 8);                               \
    } while (0)

#define COMPUTE_S(buf_, dc_) do {                                                  \
    _Pragma("unroll")                                                              \
    for (int _s = 0; _s < 2; _s++) {                                               \
        bf16x8 _qf = *(const bf16x8*)(&Qs[0][0] + (qcol*16 + c) * 776 + (dc_)*64 + _s*32 + g*8); \
        _Pragma("unroll")                                                          \
        for (int _f = 0; _f < 4; _f++) {                                           \
            int _r = kvh*64 + _f*16 + c;                                           \
            int _phys = (_s*4 + g) ^ (_r & 7);                                     \
            bf16x8 _kf = *(const bf16x8*)((buf_) + _r*128 + _phys*16);             \
            sacc[_f] = __builtin_amdgcn_mfma_f32_16x16x32_bf16(_kf, _qf, sacc[_f], 0, 0, 0); \
        } } } while (0)

#define COMPUTE_G() do {                                                           \
    _Pragma("unroll")                                                              \
    for (int _s = 0; _s < 2; _s++) {                                               \
        bf16x8 _gq = *(const bf16x8*)(&gwq[0][0] + (qcol*16 + c) * 72 + _s*32 + g*8); \
        _Pragma("unroll")                                                          \
        for (int _f = 0; _f < 4; _f++) {                                           \
            bf16x8 _gk = *(const bf16x8*)((const ushort_t*)gwkP + (kvh*64 + _f*16 + c) * 72 + _s*32 + g*8); \
            gacc[_f] = __builtin_amdgcn_mfma_f32_16x16x32_bf16(_gk, _gq, gacc[_f], 0, 0, 0); \
        } } } while (0)

#define COMPUTE_PV(buf_, ci_) do {                                                 \
    _Pragma("unroll")                                                              \
    for (int _ks = 0; _ks < 4; _ks++) {                                            \
        _Pragma("unroll")                                                          \
        for (int _df = 0; _df < 4; _df++) {                                        \
            int _d = _df*16 + c;                                                   \
            int _slot = _ks*4 + g;                                                 \
            int _phys = (_slot & 8) | ((_slot & 7) ^ (_d & 7));                    \
            bf16x8 _vf = *(const bf16x8*)((buf_) + _d*256 + _phys*16);             \
            acc[((ci_)*2+0)*4+_df] = __builtin_amdgcn_mfma_f32_16x16x32_bf16(pfrag[0][_ks], _vf, acc[((ci_)*2+0)*4+_df], 0, 0, 0); \
            acc[((ci_)*2+1)*4+_df] = __builtin_amdgcn_mfma_f32_16x16x32_bf16(pfrag[1][_ks], _vf, acc[((ci_)*2+1)*4+_df], 0, 0, 0); \
        } } } while (0)

__global__ __launch_bounds__(512, 2) void flash_mfma(
    const ushort_t* __restrict__ QB, const ushort_t* __restrict__ KB,
    const ushort_t* __restrict__ VT, const ushort_t* __restrict__ GWP,
    const ushort_t* __restrict__ GZ, const float* __restrict__ alpha_p,
    float* __restrict__ OP)
{
    __shared__ __align__(16) ushort_t Qs[64][776];   // 99328 B
    __shared__ __align__(16) char bufA[16384];       // K:[128][64] or Vt:[64][128], swizzled
    __shared__ __align__(16) char bufB[16384];
    __shared__ __align__(16) ushort_t gwq[64][72];   // 9216 B
    __shared__ __align__(16) char gwkP[18432];       // gwk [128][72] / P [64][136]
    __shared__ float smx[2][4][16];
    __shared__ float sml[2][4][16];
    __shared__ float fshare[64];
    __shared__ float lshare[64];

    const int tid = threadIdx.x;
    const int w = tid >> 6;
    const int lane = tid & 63;
    const int c = lane & 15;
    const int g = lane >> 4;
    const int b = blockIdx.y;
    const int n0 = blockIdx.x * 64;
    const int qcol = w & 3, kvh = w >> 2;
    const int qh = w & 1, dgrp = w >> 1;
    const int st_r4 = tid >> 2, st_p4 = tid & 3;
    const int st_r8 = tid >> 3, st_p8 = tid & 7;

    const ushort_t* Qg = QB + ((size_t)b * CN + n0) * CD;
    const ushort_t* Kg = KB + (size_t)b * CN * CD;
    const ushort_t* Vg = VT + (size_t)b * CD * CN;     // [768][2048]
    const ushort_t* Gg = GWP + (size_t)b * CN * 64;

    // prologue: Q, gwq, gwk(tile0), K0(tile0)
    {
        const ushort_t* src = Qg + (size_t)st_r8 * CD + st_p8 * 96;
        ushort_t* dst = &Qs[st_r8][st_p8 * 96];
#pragma unroll
        for (int i = 0; i < 12; i++)
            *(uint4*)(dst + i * 8) = *(const uint4*)(src + i * 8);
        *(uint4*)(&gwq[st_r8][st_p8 * 8]) = *(const uint4*)(Gg + (size_t)(n0 + st_r8) * 64 + st_p8 * 8);
    }
    STAGE_GWK(0);
    STAGE_K(bufA, 0, 0);
    __syncthreads();

    f32x4 acc[24];
#pragma unroll
    for (int i = 0; i < 24; i++) acc[i] = (f32x4){0.f, 0.f, 0.f, 0.f};
    float mrow = -1e30f, lrow = 0.f;
    bf16x8 pfrag[2][4];

#pragma unroll 1
    for (int kt = 0; kt < 16; ++kt) {
        const int kv0 = kt * 128;
        f32x4 sacc[4], gacc[4];
#pragma unroll
        for (int f = 0; f < 4; f++) {
            sacc[f] = (f32x4){0.f, 0.f, 0.f, 0.f};
            gacc[f] = (f32x4){0.f, 0.f, 0.f, 0.f};
        }
        COMPUTE_G();

        // ---- S phase: 12 d-chunks, ping-pong bufA/bufB ----
#pragma unroll
        for (int dc = 0; dc < 12; ++dc) {
            char* cur = (dc & 1) ? bufB : bufA;
            char* nxt = (dc & 1) ? bufA : bufB;
            if (dc < 11) { STAGE_K(nxt, kv0, dc + 1); }
            else { STAGE_V(bufA, kv0, 0); }
            COMPUTE_S(cur, dc);
            __syncthreads();
        }

        // ---- softmax (S^T frags: lane holds 16 kv for q = qcol*16+c) ----
        float z[4][4], pex[4][4];
        float pmax = -1e30f;
#pragma unroll
        for (int f = 0; f < 4; f++)
#pragma unroll
            for (int r = 0; r < 4; r++) {
                float zz = sacc[f][r] * 0.03608439182435161f * gacc[f][r];
                z[f][r] = zz;
                pmax = fmaxf(pmax, zz);
            }
        pmax = fmaxf(pmax, __shfl_xor(pmax, 16, 64));
        pmax = fmaxf(pmax, __shfl_xor(pmax, 32, 64));
        if (g == 0) smx[kvh][qcol][c] = pmax;
        __syncthreads();
        float tmax = fmaxf(pmax, smx[1 - kvh][qcol][c]);
        float mnew = fmaxf(mrow, tmax);
        float fsc = __expf(mrow - mnew);
        float psum = 0.f;
#pragma unroll
        for (int f = 0; f < 4; f++)
#pragma unroll
            for (int r = 0; r < 4; r++) {
                float e = __expf(z[f][r] - mnew);
                pex[f][r] = e;
                psum += e;
            }
        psum += __shfl_xor(psum, 16, 64);
        psum += __shfl_xor(psum, 32, 64);
        if (g == 0) {
            sml[kvh][qcol][c] = psum;
            if (kvh == 0) fshare[qcol * 16 + c] = fsc;
        }
        __syncthreads();
        float tsum = psum + sml[1 - kvh][qcol][c];
        lrow = lrow * fsc + tsum;
        mrow = mnew;
        // write P (bf16) into gwkP as [64][136]
        {
            ushort_t* P = (ushort_t*)gwkP;
#pragma unroll
            for (int f = 0; f < 4; f++)
#pragma unroll
                for (int r = 0; r < 4; r++) {
                    int kv = kvh * 64 + f * 16 + g * 4 + r;
                    P[(qcol * 16 + c) * 136 + kv] = f2bf(pex[f][r]);
                }
        }
        __syncthreads();

        // ---- PV prep: P frags + rescale ----
        {
            const ushort_t* P = (const ushort_t*)gwkP;
#pragma unroll
            for (int qf = 0; qf < 2; qf++)
#pragma unroll
                for (int ks = 0; ks < 4; ks++)
                    pfrag[qf][ks] = *(const bf16x8*)(P + (qh * 32 + qf * 16 + c) * 136 + ks * 32 + g * 8);
            float fv[2][4];
#pragma unroll
            for (int qf = 0; qf < 2; qf++)
#pragma unroll
                for (int r = 0; r < 4; r++)
                    fv[qf][r] = fshare[qh * 32 + qf * 16 + g * 4 + r];
#pragma unroll
            for (int ci = 0; ci < 3; ci++)
#pragma unroll
                for (int qf = 0; qf < 2; qf++)
#pragma unroll
                    for (int df = 0; df < 4; df++)
#pragma unroll
                        for (int r = 0; r < 4; r++)
                            acc[(ci * 2 + qf) * 4 + df][r] *= fv[qf][r];
        }

        // ---- PV phase: 12 d-chunks ----
#pragma unroll
        for (int dc2 = 0; dc2 < 12; ++dc2) {
            char* cur = (dc2 & 1) ? bufB : bufA;
            char* nxt = (dc2 & 1) ? bufA : bufB;
            if (dc2 < 11) { STAGE_V(nxt, kv0, dc2 + 1); }
            else if (kt < 15) { STAGE_K(bufA, kv0 + 128, 0); STAGE_GWK(kv0 + 128); }
            if ((dc2 & 3) == dgrp) { COMPUTE_PV(cur, (dc2 >> 2)); }
            __syncthreads();
        }
    }

    // ---- epilogue ----
    if (g == 0 && kvh == 0) lshare[qcol * 16 + c] = lrow;
    __syncthreads();
    const float aa = sigmoidf_(alpha_p[0]);
    const ushort_t* GZb = GZ + ((size_t)b * CN + n0) * CD;
    float* OPb = OP + ((size_t)b * CN + n0) * CD;
#pragma unroll
    for (int qf = 0; qf < 2; qf++) {
        float linv[4];
#pragma unroll
        for (int r = 0; r < 4; r++)
            linv[r] = 1.f / lshare[qh * 32 + qf * 16 + g * 4 + r];
#pragma unroll
        for (int ci = 0; ci < 3; ci++) {
            const int dc2 = dgrp + ci * 4;
#pragma unroll
            for (int df = 0; df < 4; df++) {
                f32x4 av = acc[(ci * 2 + qf) * 4 + df];
#pragma unroll
                for (int r = 0; r < 4; r++) {
                    int q = qh * 32 + qf * 16 + g * 4 + r;
                    int d = dc2 * 64 + df * 16 + c;
                    float gzv = bf2f(GZb[(size_t)q * CD + d]);
                    OPb[(size_t)q * CD + d] = (1.f - aa) * av[r] * linv[r] + aa * gzv;
                }
            }
        }
    }
}

// -------------------------------------------------------------------------
extern "C" void kernel_launch(void* const* d_in, const int* in_sizes, int n_in,
                              void* d_out, int out_size, void* d_ws, size_t ws_size,
                              hipStream_t stream) {
    const float* x      = (const float*)d_in[0];
    const float* W_qkv  = (const float*)d_in[1];
    const float* b_qkv  = (const float*)d_in[2];
    const float* W_proj = (const float*)d_in[3];
    const float* b_proj = (const float*)d_in[4];
    const float* W_gp   = (const float*)d_in[5];
    const float* alpha  = (const float*)d_in[6];
    float* out = (float*)d_out;

    const size_t BND  = (size_t)CB * CN * CD;        // 12,582,912 elems
    const size_t SZ_BF = BND * 2;                    // 25,165,824 B
    const size_t SZ_GW = (size_t)CB * CN * NG * 4;   // 3,211,264 B
    const size_t SZ_GWP = (size_t)CB * CN * 64 * 2;  // 2,097,152 B
    const size_t SZ_Z  = (size_t)CB * NG * CD * 4;   // 1,204,224 B
    const size_t SZ_OP = BND * 4;                    // 50,331,648 B
    const size_t need = 5 * SZ_BF + SZ_GW + SZ_GWP + SZ_Z + SZ_OP;  // ~183 MB
    if (ws_size < need) {
        ws_fail_marker<<<1, 1, 0, stream>>>(out);
        return;
    }
    char* p = (char*)d_ws;
    ushort_t* qb  = (ushort_t*)p; p += SZ_BF;
    ushort_t* kb  = (ushort_t*)p; p += SZ_BF;
    ushort_t* vb  = (ushort_t*)p; p += SZ_BF;
    ushort_t* vt  = (ushort_t*)p; p += SZ_BF;
    ushort_t* gz  = (ushort_t*)p; p += SZ_BF;
    float*    gw  = (float*)p;    p += SZ_GW;
    ushort_t* gwp = (ushort_t*)p; p += SZ_GWP;
    float*    Zb  = (float*)p;    p += SZ_Z;
    float*    op  = (float*)p;    p += SZ_OP;

    hipMemsetAsync(Zb, 0, SZ_Z, stream);
    qkv_gemm<<<dim3(128, 18), 256, 0, stream>>>(x, W_qkv, b_qkv, qb, kb, vb);
    group_weights<<<dim3(4096), 256, 0, stream>>>(vb, W_gp, gw, gwp);
    z_accum<<<dim3(8, 3, 16), 256, 0, stream>>>(vb, gw, Zb);
    gz_kernel<<<dim3(16, 3, 8), 256, 0, stream>>>(gw, Zb, gz);
    vt_transpose<<<dim3(32, 12, 8), 256, 0, stream>>>(vb, vt);
    flash_mfma<<<dim3(32, 8), 512, 0, stream>>>(qb, kb, vt, gwp, gz, alpha, op);
    proj_gemm<<<dim3(128, 6), 256, 0, stream>>>(op, W_proj, b_proj, out);
}

// Round 3
// 660.417 us; speedup vs baseline: 13.2931x; 2.2764x over previous
//
#include <hip/hip_runtime.h>
#include <hip/hip_bf16.h>
#include <math.h>

// Problem constants
#define CB 8        // batch
#define CN 2048     // seq len
#define CD 768      // dim
#define CDQKV 2304  // 3*dim
#define NG 49       // groups

typedef unsigned short ushort_t;
typedef __attribute__((ext_vector_type(8))) short bf16x8;
typedef __attribute__((ext_vector_type(4))) float f32x4;

__device__ __forceinline__ float bf2f(ushort_t u) {
    unsigned int x = ((unsigned int)u) << 16;
    return __builtin_bit_cast(float, x);
}
__device__ __forceinline__ ushort_t f2bf(float f) {
    unsigned int u = __builtin_bit_cast(unsigned int, f);
    u += 0x7fff + ((u >> 16) & 1);   // RNE
    return (ushort_t)(u >> 16);
}
__device__ __forceinline__ float sigmoidf_(float x) { return 1.f / (1.f + __expf(-x)); }

__device__ __forceinline__ void gload_lds16(const ushort_t* g, ushort_t* l) {
    __builtin_amdgcn_global_load_lds((const __attribute__((address_space(1))) void*)g,
                                     (__attribute__((address_space(3))) void*)l, 16, 0, 0);
}

// -------------------------------------------------------------------------
__global__ void ws_fail_marker(float* out) {
    if (threadIdx.x == 0 && blockIdx.x == 0) out[0] = 31337.0f;
}

// -------------------------------------------------------------------------
// cast_x: fp32 -> bf16, 8 elems/thread
// -------------------------------------------------------------------------
__global__ __launch_bounds__(256) void cast_bf16(const float* __restrict__ X,
                                                 ushort_t* __restrict__ XB, int n)
{
    int i = (blockIdx.x * 256 + threadIdx.x) * 8;
    if (i >= n) return;
    float4 a = *(const float4*)(X + i);
    float4 b = *(const float4*)(X + i + 4);
    ushort_t t[8];
    t[0] = f2bf(a.x); t[1] = f2bf(a.y); t[2] = f2bf(a.z); t[3] = f2bf(a.w);
    t[4] = f2bf(b.x); t[5] = f2bf(b.y); t[6] = f2bf(b.z); t[7] = f2bf(b.w);
    *(uint4*)(XB + i) = *(uint4*)t;
}

// -------------------------------------------------------------------------
// wt_kernel: W [rows][cols] fp32 -> WT [cols][rows] bf16 (64x64 LDS tiles)
// grid (cols/64, rows/64)
// -------------------------------------------------------------------------
__global__ __launch_bounds__(256) void wt_kernel(const float* __restrict__ W,
                                                 ushort_t* __restrict__ WT,
                                                 int rows, int cols)
{
    __shared__ ushort_t tile[64][72];
    const int bx = blockIdx.x, by = blockIdx.y;
    const int t = threadIdx.x;
    const int r = t >> 2, cp = (t & 3) * 16;
    const float* src = W + (size_t)(by * 64 + r) * cols + bx * 64 + cp;
    ushort_t tmp[16];
#pragma unroll
    for (int i = 0; i < 16; i += 4) {
        float4 v = *(const float4*)(src + i);
        tmp[i + 0] = f2bf(v.x); tmp[i + 1] = f2bf(v.y);
        tmp[i + 2] = f2bf(v.z); tmp[i + 3] = f2bf(v.w);
    }
    *(uint4*)&tile[r][cp] = *(uint4*)tmp;
    *(uint4*)&tile[r][cp + 8] = *(uint4*)(tmp + 8);
    __syncthreads();
#pragma unroll
    for (int i = 0; i < 16; i++) tmp[i] = tile[cp + i][r];
    ushort_t* dst = WT + (size_t)(bx * 64 + r) * rows + by * 64 + cp;
    *(uint4*)dst = *(uint4*)tmp;
    *(uint4*)(dst + 8) = *(uint4*)(tmp + 8);
}

// -------------------------------------------------------------------------
// mfma_gemm: C[M][N] = A[M][768] @ B^T[N][768]^T + bias, bf16 MFMA.
// 128x128 tile, BK=64, 256 thr = 4 waves (2x2 of 64x64), double-buffered LDS,
// global_load_lds w=16, source-preswizzled XOR (rule #21), 2-barrier loop.
// OUTMODE 0: split bf16 q/k/v write.  OUTMODE 1: fp32 OUT write.
// -------------------------------------------------------------------------
#define G_STAGE(dstA_, dstB_, kt_) do {                                        \
    _Pragma("unroll")                                                          \
    for (int _p = 0; _p < 4; _p++) {                                           \
        int _idx = _p * 256 + tid;                                             \
        int _row = _idx >> 3;                                                  \
        int _lsl = (_idx & 7) ^ (_row & 7);                                    \
        gload_lds16(Ag + (size_t)(m0 + _row) * CD + (kt_) * 64 + _lsl * 8,     \
                    (dstA_) + _idx * 8);                                       \
        gload_lds16(Bg + (size_t)(n0 + _row) * CD + (kt_) * 64 + _lsl * 8,     \
                    (dstB_) + _idx * 8);                                       \
    } } while (0)

#define G_COMPUTE(srcA_, srcB_) do {                                           \
    _Pragma("unroll")                                                          \
    for (int _ks = 0; _ks < 2; _ks++) {                                        \
        bf16x8 _af[4], _bf[4];                                                 \
        _Pragma("unroll")                                                      \
        for (int _f = 0; _f < 4; _f++) {                                       \
            int _ra = wr * 64 + _f * 16 + c;                                   \
            int _pa = (_ks * 4 + g) ^ (_ra & 7);                               \
            _af[_f] = *(const bf16x8*)((srcA_) + _ra * 64 + _pa * 8);          \
            int _rb = wc * 64 + _f * 16 + c;                                   \
            int _pb = (_ks * 4 + g) ^ (_rb & 7);                               \
            _bf[_f] = *(const bf16x8*)((srcB_) + _rb * 64 + _pb * 8);          \
        }                                                                      \
        _Pragma("unroll")                                                      \
        for (int _mf = 0; _mf < 4; _mf++)                                      \
            _Pragma("unroll")                                                  \
            for (int _nf = 0; _nf < 4; _nf++)                                  \
                acc[_mf * 4 + _nf] = __builtin_amdgcn_mfma_f32_16x16x32_bf16(  \
                    _af[_mf], _bf[_nf], acc[_mf * 4 + _nf], 0, 0, 0);          \
    } } while (0)

template <int OUTMODE>
__global__ __launch_bounds__(256, 2) void mfma_gemm(
    const ushort_t* __restrict__ Ag, const ushort_t* __restrict__ Bg,
    const float* __restrict__ bias,
    ushort_t* __restrict__ Qd, ushort_t* __restrict__ Kd, ushort_t* __restrict__ Vd,
    float* __restrict__ OUT)
{
    __shared__ __align__(16) ushort_t As[2][128 * 64];
    __shared__ __align__(16) ushort_t Bs[2][128 * 64];
    const int tid = threadIdx.x;
    const int lane = tid & 63;
    const int w = tid >> 6;
    const int c = lane & 15, g = lane >> 4;
    const int wr = w >> 1, wc = w & 1;
    const int m0 = blockIdx.x * 128;
    const int n0 = blockIdx.y * 128;

    f32x4 acc[16];
#pragma unroll
    for (int i = 0; i < 16; i++) acc[i] = (f32x4){0.f, 0.f, 0.f, 0.f};

    G_STAGE(As[0], Bs[0], 0);
    __syncthreads();
#pragma unroll 1
    for (int kt = 0; kt < 12; kt++) {
        const int cur = kt & 1;
        if (kt < 11) G_STAGE(As[cur ^ 1], Bs[cur ^ 1], kt + 1);
        G_COMPUTE(As[cur], Bs[cur]);
        __syncthreads();
    }

    // epilogue: D row = g*4+r (M), col = c (N) within each 16x16 fragment
    if (OUTMODE == 0) {
        const int seg = n0 / CD;
        const int nl0 = n0 % CD;
        ushort_t* dst = (seg == 0) ? Qd : (seg == 1) ? Kd : Vd;
#pragma unroll
        for (int nf = 0; nf < 4; nf++) {
            float bv = bias[n0 + wc * 64 + nf * 16 + c];
            int n = nl0 + wc * 64 + nf * 16 + c;
#pragma unroll
            for (int mf = 0; mf < 4; mf++) {
#pragma unroll
                for (int r = 0; r < 4; r++) {
                    int m = m0 + wr * 64 + mf * 16 + g * 4 + r;
                    dst[(size_t)m * CD + n] = f2bf(acc[mf * 4 + nf][r] + bv);
                }
            }
        }
    } else {
#pragma unroll
        for (int nf = 0; nf < 4; nf++) {
            int n = n0 + wc * 64 + nf * 16 + c;
            float bv = bias[n];
#pragma unroll
            for (int mf = 0; mf < 4; mf++) {
#pragma unroll
                for (int r = 0; r < 4; r++) {
                    int m = m0 + wr * 64 + mf * 16 + g * 4 + r;
                    OUT[(size_t)m * CD + n] = acc[mf * 4 + nf][r] + bv;
                }
            }
        }
    }
}

// -------------------------------------------------------------------------
// K2: gw = softmax(gelu_exact(v @ W_gp)); writes fp32 gw + zero-padded bf16 gwp[.][64]
// -------------------------------------------------------------------------
__global__ void group_weights(const ushort_t* __restrict__ V, const float* __restrict__ Wg,
                              float* __restrict__ GW, ushort_t* __restrict__ GWP)
{
    __shared__ float vrow[4][CD];
    const int wid = threadIdx.x >> 6;
    const int lane = threadIdx.x & 63;
    const int row = blockIdx.x * 4 + wid;
    const ushort_t* vsrc = V + (size_t)row * CD;
    for (int i = lane * 4; i < CD; i += 256) {
        uint2 u = *(const uint2*)(vsrc + i);
        vrow[wid][i + 0] = bf2f((ushort_t)(u.x & 0xffff));
        vrow[wid][i + 1] = bf2f((ushort_t)(u.x >> 16));
        vrow[wid][i + 2] = bf2f((ushort_t)(u.y & 0xffff));
        vrow[wid][i + 3] = bf2f((ushort_t)(u.y >> 16));
    }
    __syncthreads();

    float dot = 0.f;
    if (lane < NG) {
        for (int k = 0; k < CD; k++) dot = fmaf(vrow[wid][k], Wg[k * NG + lane], dot);
    }
    float gl = (lane < NG) ? 0.5f * dot * (1.f + erff(dot * 0.7071067811865475f)) : -1e30f;
    float mx = gl;
#pragma unroll
    for (int s = 32; s > 0; s >>= 1) mx = fmaxf(mx, __shfl_xor(mx, s, 64));
    float e = (lane < NG) ? __expf(gl - mx) : 0.f;
    float sum = e;
#pragma unroll
    for (int s = 32; s > 0; s >>= 1) sum += __shfl_xor(sum, s, 64);
    float wv = e / sum;
    if (lane < NG) GW[(size_t)row * NG + lane] = wv;
    GWP[(size_t)row * 64 + lane] = (lane < NG) ? f2bf(wv) : (ushort_t)0;
}

// -------------------------------------------------------------------------
// K3: Z[b][g][d] = sum_n gw[b][n][g] * v[b][n][d]
// -------------------------------------------------------------------------
__global__ void z_accum(const ushort_t* __restrict__ V, const float* __restrict__ GW,
                        float* __restrict__ Z)
{
    const int b = blockIdx.x;
    const int d = blockIdx.y * 256 + threadIdx.x;
    const int n0 = blockIdx.z * 128;
    float acc[NG];
#pragma unroll
    for (int g = 0; g < NG; g++) acc[g] = 0.f;
    const ushort_t* vb = V + (size_t)b * CN * CD;
    const float* gwb = GW + (size_t)b * CN * NG;
    for (int n = n0; n < n0 + 128; ++n) {
        float vd = bf2f(vb[(size_t)n * CD + d]);
        const float* gr = gwb + (size_t)n * NG;
#pragma unroll
        for (int g = 0; g < NG; g++) acc[g] = fmaf(gr[g], vd, acc[g]);
    }
    float* zb = Z + (size_t)b * NG * CD;
    for (int g = 0; g < NG; g++) atomicAdd(&zb[(size_t)g * CD + d], acc[g]);
}

// -------------------------------------------------------------------------
// K3b: GZ[n][d] = sum_g gw[n][g] * Z[b][g][d]   (bf16 out)
// -------------------------------------------------------------------------
__global__ __launch_bounds__(256) void gz_kernel(const float* __restrict__ GWf,
                                                 const float* __restrict__ Z,
                                                 ushort_t* __restrict__ GZ)
{
    __shared__ float Zs[NG][256];
    const int nb = blockIdx.x, dc = blockIdx.y, b = blockIdx.z;
    const int tid = threadIdx.x;
    const float* Zb = Z + (size_t)b * NG * CD + dc * 256;
    for (int idx = tid; idx < NG * 256; idx += 256) {
        int gg = idx >> 8, dd = idx & 255;
        Zs[gg][dd] = Zb[(size_t)gg * CD + dd];
    }
    __syncthreads();
    const int n0 = b * CN + nb * 128;
    for (int n = 0; n < 128; n++) {
        const float* gr = GWf + (size_t)(n0 + n) * NG;
        float a = 0.f;
#pragma unroll
        for (int gg = 0; gg < NG; gg++) a = fmaf(gr[gg], Zs[gg][tid], a);
        GZ[(size_t)(n0 + n) * CD + dc * 256 + tid] = f2bf(a);
    }
}

// -------------------------------------------------------------------------
// K3c: vt[b][d][n] = v[b][n][d]  (bf16 transpose), 64x64 tiles
// -------------------------------------------------------------------------
__global__ __launch_bounds__(256) void vt_transpose(const ushort_t* __restrict__ VB,
                                                    ushort_t* __restrict__ VT)
{
    __shared__ ushort_t tile[64][72];
    const int bx = blockIdx.x, by = blockIdx.y, b = blockIdx.z;
    const int t = threadIdx.x;
    const int r = t >> 2, cp = (t & 3) * 16;
    const ushort_t* src = VB + ((size_t)b * CN + bx * 64 + r) * CD + by * 64 + cp;
    *(uint4*)&tile[r][cp] = *(const uint4*)src;
    *(uint4*)&tile[r][cp + 8] = *(const uint4*)(src + 8);
    __syncthreads();
    ushort_t tmp[16];
#pragma unroll
    for (int i = 0; i < 16; i++) tmp[i] = tile[cp + i][r];
    ushort_t* dst = VT + ((size_t)b * CD + by * 64 + r) * CN + bx * 64 + cp;
    *(uint4*)dst = *(uint4*)tmp;
    *(uint4*)(dst + 8) = *(uint4*)(tmp + 8);
}

// -------------------------------------------------------------------------
// K4: MFMA flash attention with group multiplier (unchanged except bf16 OP out)
// -------------------------------------------------------------------------
#define STAGE_K(buf_, kvb_, dc_) do {                                              \
    const ushort_t* _src = Kg + (size_t)((kvb_) + st_r4) * CD + (dc_) * 64;        \
    _Pragma("unroll")                                                              \
    for (int _u = 0; _u < 2; _u++) {                                               \
        int _slot = st_p4 * 2 + _u;                                               \
        int _phys = _slot ^ (st_r4 & 7);                                          \
        *(uint4*)((buf_) + st_r4 * 128 + _phys * 16) = *(const uint4*)(_src + _slot * 8); \
    } } while (0)

#define STAGE_V(buf_, kvb_, dc2_) do {                                             \
    const ushort_t* _src = Vg + (size_t)((dc2_) * 64 + st_r8) * CN + (kvb_);       \
    _Pragma("unroll")                                                              \
    for (int _u = 0; _u < 2; _u++) {                                               \
        int _slot = st_p8 * 2 + _u;                                               \
        int _phys = (_slot & 8) | ((_slot & 7) ^ (st_r8 & 7));                    \
        *(uint4*)((buf_) + st_r8 * 256 + _phys * 16) = *(const uint4*)(_src + _slot * 8); \
    } } while (0)

#define STAGE_GWK(kvb_) do {                                                       \
    const ushort_t* _src = Gg + (size_t)((kvb_) + st_r4) * 64 + st_p4 * 16;        \
    ushort_t* _dst = (ushort_t*)gwkP + st_r4 * 72 + st_p4 * 16;                    \
    *(uint4*)(_dst) = *(const uint4*)(_src);                                       \
    *(uint4*)(_dst + 8) = *(const uint4*)(_src + 8);                               \
    } while (0)

#define COMPUTE_S(buf_, dc_) do {                                                  \
    _Pragma("unroll")                                                              \
    for (int _s = 0; _s < 2; _s++) {                                               \
        bf16x8 _qf = *(const bf16x8*)(&Qs[0][0] + (qcol*16 + c) * 776 + (dc_)*64 + _s*32 + g*8); \
        _Pragma("unroll")                                                          \
        for (int _f = 0; _f < 4; _f++) {                                           \
            int _r = kvh*64 + _f*16 + c;                                           \
            int _phys = (_s*4 + g) ^ (_r & 7);                                     \
            bf16x8 _kf = *(const bf16x8*)((buf_) + _r*128 + _phys*16);             \
            sacc[_f] = __builtin_amdgcn_mfma_f32_16x16x32_bf16(_kf, _qf, sacc[_f], 0, 0, 0); \
        } } } while (0)

#define COMPUTE_G() do {                                                           \
    _Pragma("unroll")                                                              \
    for (int _s = 0; _s < 2; _s++) {                                               \
        bf16x8 _gq = *(const bf16x8*)(&gwq[0][0] + (qcol*16 + c) * 72 + _s*32 + g*8); \
        _Pragma("unroll")                                                          \
        for (int _f = 0; _f < 4; _f++) {                                           \
            bf16x8 _gk = *(const bf16x8*)((const ushort_t*)gwkP + (kvh*64 + _f*16 + c) * 72 + _s*32 + g*8); \
            gacc[_f] = __builtin_amdgcn_mfma_f32_16x16x32_bf16(_gk, _gq, gacc[_f], 0, 0, 0); \
        } } } while (0)

#define COMPUTE_PV(buf_, ci_) do {                                                 \
    _Pragma("unroll")                                                              \
    for (int _ks = 0; _ks < 4; _ks++) {                                            \
        _Pragma("unroll")                                                          \
        for (int _df = 0; _df < 4; _df++) {                                        \
            int _d = _df*16 + c;                                                   \
            int _slot = _ks*4 + g;                                                 \
            int _phys = (_slot & 8) | ((_slot & 7) ^ (_d & 7));                    \
            bf16x8 _vf = *(const bf16x8*)((buf_) + _d*256 + _phys*16);             \
            acc[((ci_)*2+0)*4+_df] = __builtin_amdgcn_mfma_f32_16x16x32_bf16(pfrag[0][_ks], _vf, acc[((ci_)*2+0)*4+_df], 0, 0, 0); \
            acc[((ci_)*2+1)*4+_df] = __builtin_amdgcn_mfma_f32_16x16x32_bf16(pfrag[1][_ks], _vf, acc[((ci_)*2+1)*4+_df], 0, 0, 0); \
        } } } while (0)

__global__ __launch_bounds__(512, 2) void flash_mfma(
    const ushort_t* __restrict__ QB, const ushort_t* __restrict__ KB,
    const ushort_t* __restrict__ VT, const ushort_t* __restrict__ GWP,
    const ushort_t* __restrict__ GZ, const float* __restrict__ alpha_p,
    ushort_t* __restrict__ OP)
{
    __shared__ __align__(16) ushort_t Qs[64][776];   // 99328 B
    __shared__ __align__(16) char bufA[16384];       // K:[128][64] or Vt:[64][128], swizzled
    __shared__ __align__(16) char bufB[16384];
    __shared__ __align__(16) ushort_t gwq[64][72];   // 9216 B
    __shared__ __align__(16) char gwkP[18432];       // gwk [128][72] / P [64][136]
    __shared__ float smx[2][4][16];
    __shared__ float sml[2][4][16];
    __shared__ float fshare[64];
    __shared__ float lshare[64];

    const int tid = threadIdx.x;
    const int w = tid >> 6;
    const int lane = tid & 63;
    const int c = lane & 15;
    const int g = lane >> 4;
    const int b = blockIdx.y;
    const int n0 = blockIdx.x * 64;
    const int qcol = w & 3, kvh = w >> 2;
    const int qh = w & 1, dgrp = w >> 1;
    const int st_r4 = tid >> 2, st_p4 = tid & 3;
    const int st_r8 = tid >> 3, st_p8 = tid & 7;

    const ushort_t* Qg = QB + ((size_t)b * CN + n0) * CD;
    const ushort_t* Kg = KB + (size_t)b * CN * CD;
    const ushort_t* Vg = VT + (size_t)b * CD * CN;     // [768][2048]
    const ushort_t* Gg = GWP + (size_t)b * CN * 64;

    {
        const ushort_t* src = Qg + (size_t)st_r8 * CD + st_p8 * 96;
        ushort_t* dst = &Qs[st_r8][st_p8 * 96];
#pragma unroll
        for (int i = 0; i < 12; i++)
            *(uint4*)(dst + i * 8) = *(const uint4*)(src + i * 8);
        *(uint4*)(&gwq[st_r8][st_p8 * 8]) = *(const uint4*)(Gg + (size_t)(n0 + st_r8) * 64 + st_p8 * 8);
    }
    STAGE_GWK(0);
    STAGE_K(bufA, 0, 0);
    __syncthreads();

    f32x4 acc[24];
#pragma unroll
    for (int i = 0; i < 24; i++) acc[i] = (f32x4){0.f, 0.f, 0.f, 0.f};
    float mrow = -1e30f, lrow = 0.f;
    bf16x8 pfrag[2][4];

#pragma unroll 1
    for (int kt = 0; kt < 16; ++kt) {
        const int kv0 = kt * 128;
        f32x4 sacc[4], gacc[4];
#pragma unroll
        for (int f = 0; f < 4; f++) {
            sacc[f] = (f32x4){0.f, 0.f, 0.f, 0.f};
            gacc[f] = (f32x4){0.f, 0.f, 0.f, 0.f};
        }
        COMPUTE_G();

#pragma unroll
        for (int dc = 0; dc < 12; ++dc) {
            char* cur = (dc & 1) ? bufB : bufA;
            char* nxt = (dc & 1) ? bufA : bufB;
            if (dc < 11) { STAGE_K(nxt, kv0, dc + 1); }
            else { STAGE_V(bufA, kv0, 0); }
            COMPUTE_S(cur, dc);
            __syncthreads();
        }

        float z[4][4], pex[4][4];
        float pmax = -1e30f;
#pragma unroll
        for (int f = 0; f < 4; f++)
#pragma unroll
            for (int r = 0; r < 4; r++) {
                float zz = sacc[f][r] * 0.03608439182435161f * gacc[f][r];
                z[f][r] = zz;
                pmax = fmaxf(pmax, zz);
            }
        pmax = fmaxf(pmax, __shfl_xor(pmax, 16, 64));
        pmax = fmaxf(pmax, __shfl_xor(pmax, 32, 64));
        if (g == 0) smx[kvh][qcol][c] = pmax;
        __syncthreads();
        float tmax = fmaxf(pmax, smx[1 - kvh][qcol][c]);
        float mnew = fmaxf(mrow, tmax);
        float fsc = __expf(mrow - mnew);
        float psum = 0.f;
#pragma unroll
        for (int f = 0; f < 4; f++)
#pragma unroll
            for (int r = 0; r < 4; r++) {
                float e = __expf(z[f][r] - mnew);
                pex[f][r] = e;
                psum += e;
            }
        psum += __shfl_xor(psum, 16, 64);
        psum += __shfl_xor(psum, 32, 64);
        if (g == 0) {
            sml[kvh][qcol][c] = psum;
            if (kvh == 0) fshare[qcol * 16 + c] = fsc;
        }
        __syncthreads();
        float tsum = psum + sml[1 - kvh][qcol][c];
        lrow = lrow * fsc + tsum;
        mrow = mnew;
        {
            ushort_t* P = (ushort_t*)gwkP;
#pragma unroll
            for (int f = 0; f < 4; f++)
#pragma unroll
                for (int r = 0; r < 4; r++) {
                    int kv = kvh * 64 + f * 16 + g * 4 + r;
                    P[(qcol * 16 + c) * 136 + kv] = f2bf(pex[f][r]);
                }
        }
        __syncthreads();

        {
            const ushort_t* P = (const ushort_t*)gwkP;
#pragma unroll
            for (int qf = 0; qf < 2; qf++)
#pragma unroll
                for (int ks = 0; ks < 4; ks++)
                    pfrag[qf][ks] = *(const bf16x8*)(P + (qh * 32 + qf * 16 + c) * 136 + ks * 32 + g * 8);
            float fv[2][4];
#pragma unroll
            for (int qf = 0; qf < 2; qf++)
#pragma unroll
                for (int r = 0; r < 4; r++)
                    fv[qf][r] = fshare[qh * 32 + qf * 16 + g * 4 + r];
#pragma unroll
            for (int ci = 0; ci < 3; ci++)
#pragma unroll
                for (int qf = 0; qf < 2; qf++)
#pragma unroll
                    for (int df = 0; df < 4; df++)
#pragma unroll
                        for (int r = 0; r < 4; r++)
                            acc[(ci * 2 + qf) * 4 + df][r] *= fv[qf][r];
        }

#pragma unroll
        for (int dc2 = 0; dc2 < 12; ++dc2) {
            char* cur = (dc2 & 1) ? bufB : bufA;
            char* nxt = (dc2 & 1) ? bufA : bufB;
            if (dc2 < 11) { STAGE_V(nxt, kv0, dc2 + 1); }
            else if (kt < 15) { STAGE_K(bufA, kv0 + 128, 0); STAGE_GWK(kv0 + 128); }
            if ((dc2 & 3) == dgrp) { COMPUTE_PV(cur, (dc2 >> 2)); }
            __syncthreads();
        }
    }

    if (g == 0 && kvh == 0) lshare[qcol * 16 + c] = lrow;
    __syncthreads();
    const float aa = sigmoidf_(alpha_p[0]);
    const ushort_t* GZb = GZ + ((size_t)b * CN + n0) * CD;
    ushort_t* OPb = OP + ((size_t)b * CN + n0) * CD;
#pragma unroll
    for (int qf = 0; qf < 2; qf++) {
        float linv[4];
#pragma unroll
        for (int r = 0; r < 4; r++)
            linv[r] = 1.f / lshare[qh * 32 + qf * 16 + g * 4 + r];
#pragma unroll
        for (int ci = 0; ci < 3; ci++) {
            const int dc2 = dgrp + ci * 4;
#pragma unroll
            for (int df = 0; df < 4; df++) {
                f32x4 av = acc[(ci * 2 + qf) * 4 + df];
#pragma unroll
                for (int r = 0; r < 4; r++) {
                    int q = qh * 32 + qf * 16 + g * 4 + r;
                    int d = dc2 * 64 + df * 16 + c;
                    float gzv = bf2f(GZb[(size_t)q * CD + d]);
                    OPb[(size_t)q * CD + d] = f2bf((1.f - aa) * av[r] * linv[r] + aa * gzv);
                }
            }
        }
    }
}

// -------------------------------------------------------------------------
extern "C" void kernel_launch(void* const* d_in, const int* in_sizes, int n_in,
                              void* d_out, int out_size, void* d_ws, size_t ws_size,
                              hipStream_t stream) {
    const float* x      = (const float*)d_in[0];
    const float* W_qkv  = (const float*)d_in[1];
    const float* b_qkv  = (const float*)d_in[2];
    const float* W_proj = (const float*)d_in[3];
    const float* b_proj = (const float*)d_in[4];
    const float* W_gp   = (const float*)d_in[5];
    const float* alpha  = (const float*)d_in[6];
    float* out = (float*)d_out;

    const size_t BND   = (size_t)CB * CN * CD;        // 12,582,912 elems
    const size_t SZ_BF = BND * 2;                     // 25,165,824 B
    const size_t SZ_WQT = (size_t)CDQKV * CD * 2;     // 3,538,944 B
    const size_t SZ_WPT = (size_t)CD * CD * 2;        // 1,179,648 B
    const size_t SZ_GW  = (size_t)CB * CN * NG * 4;   // 3,211,264 B
    const size_t SZ_GWP = (size_t)CB * CN * 64 * 2;   // 2,097,152 B
    const size_t SZ_Z   = (size_t)CB * NG * CD * 4;   // 1,204,224 B
    const size_t need = 7 * SZ_BF + SZ_WQT + SZ_WPT + SZ_GW + SZ_GWP + SZ_Z;  // ~187 MB
    if (ws_size < need) {
        ws_fail_marker<<<1, 1, 0, stream>>>(out);
        return;
    }
    char* p = (char*)d_ws;
    ushort_t* xb  = (ushort_t*)p; p += SZ_BF;
    ushort_t* qb  = (ushort_t*)p; p += SZ_BF;
    ushort_t* kb  = (ushort_t*)p; p += SZ_BF;
    ushort_t* vb  = (ushort_t*)p; p += SZ_BF;
    ushort_t* vt  = (ushort_t*)p; p += SZ_BF;
    ushort_t* gz  = (ushort_t*)p; p += SZ_BF;
    ushort_t* opb = (ushort_t*)p; p += SZ_BF;
    ushort_t* wqt = (ushort_t*)p; p += SZ_WQT;
    ushort_t* wpt = (ushort_t*)p; p += SZ_WPT;
    float*    gw  = (float*)p;    p += SZ_GW;
    ushort_t* gwp = (ushort_t*)p; p += SZ_GWP;
    float*    Zb  = (float*)p;    p += SZ_Z;

    hipMemsetAsync(Zb, 0, SZ_Z, stream);
    cast_bf16<<<dim3((int)(BND / 8 / 256)), 256, 0, stream>>>(x, xb, (int)BND);
    wt_kernel<<<dim3(36, 12), 256, 0, stream>>>(W_qkv, wqt, CD, CDQKV);
    wt_kernel<<<dim3(12, 12), 256, 0, stream>>>(W_proj, wpt, CD, CD);
    mfma_gemm<0><<<dim3(128, 18), 256, 0, stream>>>(xb, wqt, b_qkv, qb, kb, vb, nullptr);
    group_weights<<<dim3(4096), 256, 0, stream>>>(vb, W_gp, gw, gwp);
    z_accum<<<dim3(8, 3, 16), 256, 0, stream>>>(vb, gw, Zb);
    gz_kernel<<<dim3(16, 3, 8), 256, 0, stream>>>(gw, Zb, gz);
    vt_transpose<<<dim3(32, 12, 8), 256, 0, stream>>>(vb, vt);
    flash_mfma<<<dim3(32, 8), 512, 0, stream>>>(qb, kb, vt, gwp, gz, alpha, opb);
    mfma_gemm<1><<<dim3(128, 6), 256, 0, stream>>>(opb, wpt, b_proj, nullptr, nullptr, nullptr, out);
}

// Round 5
// 557.188 us; speedup vs baseline: 15.7559x; 1.1853x over previous
//
#include <hip/hip_runtime.h>
#include <hip/hip_bf16.h>
#include <math.h>

// Problem constants
#define CB 8        // batch
#define CN 2048     // seq len
#define CD 768      // dim
#define CDQKV 2304  // 3*dim
#define NG 49       // groups

typedef unsigned short ushort_t;
typedef __attribute__((ext_vector_type(8))) short bf16x8;
typedef __attribute__((ext_vector_type(4))) float f32x4;

__device__ __forceinline__ float bf2f(ushort_t u) {
    unsigned int x = ((unsigned int)u) << 16;
    return __builtin_bit_cast(float, x);
}
__device__ __forceinline__ ushort_t f2bf(float f) {
    unsigned int u = __builtin_bit_cast(unsigned int, f);
    u += 0x7fff + ((u >> 16) & 1);   // RNE
    return (ushort_t)(u >> 16);
}
__device__ __forceinline__ ushort_t f2h(float f) {
    _Float16 h = (_Float16)f;
    return __builtin_bit_cast(ushort_t, h);
}
__device__ __forceinline__ float h2f(ushort_t u) {
    return (float)__builtin_bit_cast(_Float16, u);
}
__device__ __forceinline__ float sigmoidf_(float x) { return 1.f / (1.f + __expf(-x)); }

__device__ __forceinline__ void gload_lds16(const ushort_t* g, ushort_t* l) {
    __builtin_amdgcn_global_load_lds((const __attribute__((address_space(1))) void*)g,
                                     (__attribute__((address_space(3))) void*)l, 16, 0, 0);
}

// -------------------------------------------------------------------------
__global__ void ws_fail_marker(float* out) {
    if (threadIdx.x == 0 && blockIdx.x == 0) out[0] = 31337.0f;
}

// -------------------------------------------------------------------------
// cast_x: fp32 -> bf16, 8 elems/thread
// -------------------------------------------------------------------------
__global__ __launch_bounds__(256) void cast_bf16(const float* __restrict__ X,
                                                 ushort_t* __restrict__ XB, int n)
{
    int i = (blockIdx.x * 256 + threadIdx.x) * 8;
    if (i >= n) return;
    float4 a = *(const float4*)(X + i);
    float4 b = *(const float4*)(X + i + 4);
    ushort_t t[8];
    t[0] = f2bf(a.x); t[1] = f2bf(a.y); t[2] = f2bf(a.z); t[3] = f2bf(a.w);
    t[4] = f2bf(b.x); t[5] = f2bf(b.y); t[6] = f2bf(b.z); t[7] = f2bf(b.w);
    *(uint4*)(XB + i) = *(uint4*)t;
}

// -------------------------------------------------------------------------
// wt_kernel: W [rows][cols] fp32 -> WT [cols][rows] bf16 (64x64 LDS tiles)
// -------------------------------------------------------------------------
__global__ __launch_bounds__(256) void wt_kernel(const float* __restrict__ W,
                                                 ushort_t* __restrict__ WT,
                                                 int rows, int cols)
{
    __shared__ ushort_t tile[64][72];
    const int bx = blockIdx.x, by = blockIdx.y;
    const int t = threadIdx.x;
    const int r = t >> 2, cp = (t & 3) * 16;
    const float* src = W + (size_t)(by * 64 + r) * cols + bx * 64 + cp;
    ushort_t tmp[16];
#pragma unroll
    for (int i = 0; i < 16; i += 4) {
        float4 v = *(const float4*)(src + i);
        tmp[i + 0] = f2bf(v.x); tmp[i + 1] = f2bf(v.y);
        tmp[i + 2] = f2bf(v.z); tmp[i + 3] = f2bf(v.w);
    }
    *(uint4*)&tile[r][cp] = *(uint4*)tmp;
    *(uint4*)&tile[r][cp + 8] = *(uint4*)(tmp + 8);
    __syncthreads();
#pragma unroll
    for (int i = 0; i < 16; i++) tmp[i] = tile[cp + i][r];
    ushort_t* dst = WT + (size_t)(bx * 64 + r) * rows + by * 64 + cp;
    *(uint4*)dst = *(uint4*)tmp;
    *(uint4*)(dst + 8) = *(uint4*)(tmp + 8);
}

// -------------------------------------------------------------------------
// Shared GEMM machinery: 128x128 tile, BK=64, 256 thr = 4 waves (2x2 of 64x64),
// double-buffered LDS via global_load_lds w=16, source-preswizzled XOR.
// -------------------------------------------------------------------------
#define GEN_STAGE(dstA_, dstB_, kt_, Abase_, Bbase_, lda_, ldb_) do {          \
    _Pragma("unroll")                                                          \
    for (int _p = 0; _p < 4; _p++) {                                           \
        int _idx = _p * 256 + tid;                                             \
        int _row = _idx >> 3;                                                  \
        int _lsl = (_idx & 7) ^ (_row & 7);                                    \
        gload_lds16((Abase_) + (size_t)_row * (lda_) + (size_t)(kt_) * 64 + _lsl * 8, \
                    (dstA_) + _idx * 8);                                       \
        gload_lds16((Bbase_) + (size_t)_row * (ldb_) + (size_t)(kt_) * 64 + _lsl * 8, \
                    (dstB_) + _idx * 8);                                       \
    } } while (0)

#define G_COMPUTE(srcA_, srcB_) do {                                           \
    _Pragma("unroll")                                                          \
    for (int _ks = 0; _ks < 2; _ks++) {                                        \
        bf16x8 _af[4], _bf[4];                                                 \
        _Pragma("unroll")                                                      \
        for (int _f = 0; _f < 4; _f++) {                                       \
            int _ra = wr * 64 + _f * 16 + c;                                   \
            int _pa = (_ks * 4 + g) ^ (_ra & 7);                               \
            _af[_f] = *(const bf16x8*)((srcA_) + _ra * 64 + _pa * 8);          \
            int _rb = wc * 64 + _f * 16 + c;                                   \
            int _pb = (_ks * 4 + g) ^ (_rb & 7);                               \
            _bf[_f] = *(const bf16x8*)((srcB_) + _rb * 64 + _pb * 8);          \
        }                                                                      \
        _Pragma("unroll")                                                      \
        for (int _mf = 0; _mf < 4; _mf++)                                      \
            _Pragma("unroll")                                                  \
            for (int _nf = 0; _nf < 4; _nf++)                                  \
                acc[_mf * 4 + _nf] = __builtin_amdgcn_mfma_f32_16x16x32_bf16(  \
                    _af[_mf], _bf[_nf], acc[_mf * 4 + _nf], 0, 0, 0);          \
    } } while (0)

// -------------------------------------------------------------------------
// mfma_gemm: C = A[M][768] @ B^T[N][768]^T + bias.
// OUTMODE 0: split bf16 q/k/v write.  OUTMODE 1: fp32 OUT write.
// -------------------------------------------------------------------------
template <int OUTMODE>
__global__ __launch_bounds__(256, 2) void mfma_gemm(
    const ushort_t* __restrict__ Ag, const ushort_t* __restrict__ Bg,
    const float* __restrict__ bias,
    ushort_t* __restrict__ Qd, ushort_t* __restrict__ Kd, ushort_t* __restrict__ Vd,
    float* __restrict__ OUT)
{
    __shared__ __align__(16) ushort_t As[2][128 * 64];
    __shared__ __align__(16) ushort_t Bs[2][128 * 64];
    const int tid = threadIdx.x;
    const int lane = tid & 63;
    const int w = tid >> 6;
    const int c = lane & 15, g = lane >> 4;
    const int wr = w >> 1, wc = w & 1;
    const int m0 = blockIdx.x * 128;
    const int n0 = blockIdx.y * 128;
    const ushort_t* Ab = Ag + (size_t)m0 * CD;
    const ushort_t* Bb = Bg + (size_t)n0 * CD;

    f32x4 acc[16];
#pragma unroll
    for (int i = 0; i < 16; i++) acc[i] = (f32x4){0.f, 0.f, 0.f, 0.f};

    GEN_STAGE(As[0], Bs[0], 0, Ab, Bb, CD, CD);
    __syncthreads();
#pragma unroll 1
    for (int kt = 0; kt < 12; kt++) {
        const int cur = kt & 1;
        if (kt < 11) GEN_STAGE(As[cur ^ 1], Bs[cur ^ 1], kt + 1, Ab, Bb, CD, CD);
        G_COMPUTE(As[cur], Bs[cur]);
        __syncthreads();
    }

    if (OUTMODE == 0) {
        const int seg = n0 / CD;
        const int nl0 = n0 % CD;
        ushort_t* dst = (seg == 0) ? Qd : (seg == 1) ? Kd : Vd;
#pragma unroll
        for (int nf = 0; nf < 4; nf++) {
            float bv = bias[n0 + wc * 64 + nf * 16 + c];
            int n = nl0 + wc * 64 + nf * 16 + c;
#pragma unroll
            for (int mf = 0; mf < 4; mf++) {
#pragma unroll
                for (int r = 0; r < 4; r++) {
                    int m = m0 + wr * 64 + mf * 16 + g * 4 + r;
                    dst[(size_t)m * CD + n] = f2bf(acc[mf * 4 + nf][r] + bv);
                }
            }
        }
    } else {
#pragma unroll
        for (int nf = 0; nf < 4; nf++) {
            int n = n0 + wc * 64 + nf * 16 + c;
            float bv = bias[n];
#pragma unroll
            for (int mf = 0; mf < 4; mf++) {
#pragma unroll
                for (int r = 0; r < 4; r++) {
                    int m = m0 + wr * 64 + mf * 16 + g * 4 + r;
                    OUT[(size_t)m * CD + n] = acc[mf * 4 + nf][r] + bv;
                }
            }
        }
    }
}

// -------------------------------------------------------------------------
// s_gemm: S[b][q][kv] = (q . k) * scale * G, fp16 out.
// G = gwq @ gwk^T via 32 extra MFMAs, operand frags straight from global.
// grid (16 qb, 16 kvb, 8 b)
// -------------------------------------------------------------------------
__global__ __launch_bounds__(256, 2) void s_gemm(
    const ushort_t* __restrict__ Qb, const ushort_t* __restrict__ Kb,
    const ushort_t* __restrict__ GWP, ushort_t* __restrict__ S)
{
    __shared__ __align__(16) ushort_t As[2][128 * 64];
    __shared__ __align__(16) ushort_t Bs[2][128 * 64];
    const int tid = threadIdx.x;
    const int lane = tid & 63;
    const int w = tid >> 6;
    const int c = lane & 15, g = lane >> 4;
    const int wr = w >> 1, wc = w & 1;
    const int b = blockIdx.z;
    const int m0 = blockIdx.x * 128;
    const int n0 = blockIdx.y * 128;
    const ushort_t* Ab = Qb + ((size_t)b * CN + m0) * CD;
    const ushort_t* Bb = Kb + ((size_t)b * CN + n0) * CD;

    f32x4 acc[16], gacc[16];
#pragma unroll
    for (int i = 0; i < 16; i++) {
        acc[i] = (f32x4){0.f, 0.f, 0.f, 0.f};
        gacc[i] = (f32x4){0.f, 0.f, 0.f, 0.f};
    }

    GEN_STAGE(As[0], Bs[0], 0, Ab, Bb, CD, CD);

    // ---- group-affinity G via MFMA; frags loaded from global (L2-hot) ----
    {
        const ushort_t* Gq = GWP + ((size_t)b * CN + m0) * 64;
        const ushort_t* Gk = GWP + ((size_t)b * CN + n0) * 64;
        bf16x8 gqf[2][4], gkf[2][4];
#pragma unroll
        for (int ks = 0; ks < 2; ks++)
#pragma unroll
            for (int f = 0; f < 4; f++) {
                gqf[ks][f] = *(const bf16x8*)(Gq + (size_t)(wr * 64 + f * 16 + c) * 64 + ks * 32 + g * 8);
                gkf[ks][f] = *(const bf16x8*)(Gk + (size_t)(wc * 64 + f * 16 + c) * 64 + ks * 32 + g * 8);
            }
#pragma unroll
        for (int ks = 0; ks < 2; ks++)
#pragma unroll
            for (int mf = 0; mf < 4; mf++)
#pragma unroll
                for (int nf = 0; nf < 4; nf++)
                    gacc[mf * 4 + nf] = __builtin_amdgcn_mfma_f32_16x16x32_bf16(
                        gqf[ks][mf], gkf[ks][nf], gacc[mf * 4 + nf], 0, 0, 0);
    }

    __syncthreads();
#pragma unroll 1
    for (int kt = 0; kt < 12; kt++) {
        const int cur = kt & 1;
        if (kt < 11) GEN_STAGE(As[cur ^ 1], Bs[cur ^ 1], kt + 1, Ab, Bb, CD, CD);
        G_COMPUTE(As[cur], Bs[cur]);
        __syncthreads();
    }

    ushort_t* Sb = S + ((size_t)b * CN + m0) * CN + n0;
    const float scale = 0.03608439182435161f;  // 768^-0.5
#pragma unroll
    for (int nf = 0; nf < 4; nf++) {
        int n = wc * 64 + nf * 16 + c;
#pragma unroll
        for (int mf = 0; mf < 4; mf++) {
#pragma unroll
            for (int r = 0; r < 4; r++) {
                int m = wr * 64 + mf * 16 + g * 4 + r;
                float z = acc[mf * 4 + nf][r] * scale * gacc[mf * 4 + nf][r];
                Sb[(size_t)m * CN + n] = f2h(z);
            }
        }
    }
}

// -------------------------------------------------------------------------
// softmax_rows: in-place row softmax over CN=2048. fp16 in, bf16 out.
// 1 wave per row, 4 rows per block; 32 vals/lane in registers.
// -------------------------------------------------------------------------
__global__ __launch_bounds__(256) void softmax_rows(ushort_t* __restrict__ SP)
{
    const int lane = threadIdx.x & 63;
    const int row = blockIdx.x * 4 + (threadIdx.x >> 6);
    ushort_t* rp = SP + (size_t)row * CN;

    float v[32];
    float mx = -1e30f;
#pragma unroll
    for (int ch = 0; ch < 4; ch++) {
        uint4 u = *(const uint4*)(rp + ch * 512 + lane * 8);
        const unsigned int uu[4] = {u.x, u.y, u.z, u.w};
#pragma unroll
        for (int j = 0; j < 4; j++) {
            float a = h2f((ushort_t)(uu[j] & 0xffff));
            float bq = h2f((ushort_t)(uu[j] >> 16));
            v[ch * 8 + j * 2] = a;
            v[ch * 8 + j * 2 + 1] = bq;
            mx = fmaxf(mx, fmaxf(a, bq));
        }
    }
#pragma unroll
    for (int s = 32; s > 0; s >>= 1) mx = fmaxf(mx, __shfl_xor(mx, s, 64));
    float sum = 0.f;
#pragma unroll
    for (int i = 0; i < 32; i++) {
        v[i] = __expf(v[i] - mx);
        sum += v[i];
    }
#pragma unroll
    for (int s = 32; s > 0; s >>= 1) sum += __shfl_xor(sum, s, 64);
    float inv = 1.f / sum;
#pragma unroll
    for (int ch = 0; ch < 4; ch++) {
        ushort_t t[8];
#pragma unroll
        for (int j = 0; j < 8; j++) t[j] = f2bf(v[ch * 8 + j] * inv);
        *(uint4*)(rp + ch * 512 + lane * 8) = *(uint4*)t;
    }
}

// -------------------------------------------------------------------------
// pv_gemm: O[b][q][d] = (1-a) * P[b][q][:] @ V[b][:][d] + a * GZ[b][q][d]
// A = P (bf16, lda=CN), B^T = vt[b][d][kv] (ldb=CN), K=2048 -> 32 k-tiles.
// grid (16 qb, 6 db, 8 b), bf16 out.
// -------------------------------------------------------------------------
__global__ __launch_bounds__(256, 2) void pv_gemm(
    const ushort_t* __restrict__ P, const ushort_t* __restrict__ VT,
    const ushort_t* __restrict__ GZ, const float* __restrict__ alpha_p,
    ushort_t* __restrict__ OP)
{
    __shared__ __align__(16) ushort_t As[2][128 * 64];
    __shared__ __align__(16) ushort_t Bs[2][128 * 64];
    const int tid = threadIdx.x;
    const int lane = tid & 63;
    const int w = tid >> 6;
    const int c = lane & 15, g = lane >> 4;
    const int wr = w >> 1, wc = w & 1;
    const int b = blockIdx.z;
    const int m0 = blockIdx.x * 128;
    const int n0 = blockIdx.y * 128;
    const ushort_t* Ab = P + ((size_t)b * CN + m0) * CN;
    const ushort_t* Bb = VT + ((size_t)b * CD + n0) * CN;

    f32x4 acc[16];
#pragma unroll
    for (int i = 0; i < 16; i++) acc[i] = (f32x4){0.f, 0.f, 0.f, 0.f};

    GEN_STAGE(As[0], Bs[0], 0, Ab, Bb, CN, CN);
    __syncthreads();
#pragma unroll 1
    for (int kt = 0; kt < 32; kt++) {
        const int cur = kt & 1;
        if (kt < 31) GEN_STAGE(As[cur ^ 1], Bs[cur ^ 1], kt + 1, Ab, Bb, CN, CN);
        G_COMPUTE(As[cur], Bs[cur]);
        __syncthreads();
    }

    const float aa = sigmoidf_(alpha_p[0]);
    const ushort_t* GZb = GZ + ((size_t)b * CN + m0) * CD;
    ushort_t* OPb = OP + ((size_t)b * CN + m0) * CD;
#pragma unroll
    for (int nf = 0; nf < 4; nf++) {
        int n = n0 + wc * 64 + nf * 16 + c;
#pragma unroll
        for (int mf = 0; mf < 4; mf++) {
#pragma unroll
            for (int r = 0; r < 4; r++) {
                int m = wr * 64 + mf * 16 + g * 4 + r;
                float gzv = bf2f(GZb[(size_t)m * CD + n]);
                OPb[(size_t)m * CD + n] = f2bf((1.f - aa) * acc[mf * 4 + nf][r] + aa * gzv);
            }
        }
    }
}

// -------------------------------------------------------------------------
// K2: gw = softmax(gelu_exact(v @ W_gp)); fp32 gw + zero-padded bf16 gwp[.][64]
// -------------------------------------------------------------------------
__global__ void group_weights(const ushort_t* __restrict__ V, const float* __restrict__ Wg,
                              float* __restrict__ GW, ushort_t* __restrict__ GWP)
{
    __shared__ float vrow[4][CD];
    const int wid = threadIdx.x >> 6;
    const int lane = threadIdx.x & 63;
    const int row = blockIdx.x * 4 + wid;
    const ushort_t* vsrc = V + (size_t)row * CD;
    for (int i = lane * 4; i < CD; i += 256) {
        uint2 u = *(const uint2*)(vsrc + i);
        vrow[wid][i + 0] = bf2f((ushort_t)(u.x & 0xffff));
        vrow[wid][i + 1] = bf2f((ushort_t)(u.x >> 16));
        vrow[wid][i + 2] = bf2f((ushort_t)(u.y & 0xffff));
        vrow[wid][i + 3] = bf2f((ushort_t)(u.y >> 16));
    }
    __syncthreads();

    float dot = 0.f;
    if (lane < NG) {
        for (int k = 0; k < CD; k++) dot = fmaf(vrow[wid][k], Wg[k * NG + lane], dot);
    }
    float gl = (lane < NG) ? 0.5f * dot * (1.f + erff(dot * 0.7071067811865475f)) : -1e30f;
    float mx = gl;
#pragma unroll
    for (int s = 32; s > 0; s >>= 1) mx = fmaxf(mx, __shfl_xor(mx, s, 64));
    float e = (lane < NG) ? __expf(gl - mx) : 0.f;
    float sum = e;
#pragma unroll
    for (int s = 32; s > 0; s >>= 1) sum += __shfl_xor(sum, s, 64);
    float wv = e / sum;
    if (lane < NG) GW[(size_t)row * NG + lane] = wv;
    GWP[(size_t)row * 64 + lane] = (lane < NG) ? f2bf(wv) : (ushort_t)0;
}

// -------------------------------------------------------------------------
// K3: Z[b][g][d] = sum_n gw[b][n][g] * v[b][n][d]
// -------------------------------------------------------------------------
__global__ void z_accum(const ushort_t* __restrict__ V, const float* __restrict__ GW,
                        float* __restrict__ Z)
{
    const int b = blockIdx.x;
    const int d = blockIdx.y * 256 + threadIdx.x;
    const int n0 = blockIdx.z * 128;
    float acc[NG];
#pragma unroll
    for (int g = 0; g < NG; g++) acc[g] = 0.f;
    const ushort_t* vb = V + (size_t)b * CN * CD;
    const float* gwb = GW + (size_t)b * CN * NG;
    for (int n = n0; n < n0 + 128; ++n) {
        float vd = bf2f(vb[(size_t)n * CD + d]);
        const float* gr = gwb + (size_t)n * NG;
#pragma unroll
        for (int g = 0; g < NG; g++) acc[g] = fmaf(gr[g], vd, acc[g]);
    }
    float* zb = Z + (size_t)b * NG * CD;
    for (int g = 0; g < NG; g++) atomicAdd(&zb[(size_t)g * CD + d], acc[g]);
}

// -------------------------------------------------------------------------
// K3b: GZ[n][d] = sum_g gw[n][g] * Z[b][g][d]   (bf16 out)
// -------------------------------------------------------------------------
__global__ __launch_bounds__(256) void gz_kernel(const float* __restrict__ GWf,
                                                 const float* __restrict__ Z,
                                                 ushort_t* __restrict__ GZ)
{
    __shared__ float Zs[NG][256];
    const int nb = blockIdx.x, dc = blockIdx.y, b = blockIdx.z;
    const int tid = threadIdx.x;
    const float* Zb = Z + (size_t)b * NG * CD + dc * 256;
    for (int idx = tid; idx < NG * 256; idx += 256) {
        int gg = idx >> 8, dd = idx & 255;
        Zs[gg][dd] = Zb[(size_t)gg * CD + dd];
    }
    __syncthreads();
    const int n0 = b * CN + nb * 128;
    for (int n = 0; n < 128; n++) {
        const float* gr = GWf + (size_t)(n0 + n) * NG;
        float a = 0.f;
#pragma unroll
        for (int gg = 0; gg < NG; gg++) a = fmaf(gr[gg], Zs[gg][tid], a);
        GZ[(size_t)(n0 + n) * CD + dc * 256 + tid] = f2bf(a);
    }
}

// -------------------------------------------------------------------------
// K3c: vt[b][d][n] = v[b][n][d]  (bf16 transpose), 64x64 tiles
// -------------------------------------------------------------------------
__global__ __launch_bounds__(256) void vt_transpose(const ushort_t* __restrict__ VB,
                                                    ushort_t* __restrict__ VT)
{
    __shared__ ushort_t tile[64][72];
    const int bx = blockIdx.x, by = blockIdx.y, b = blockIdx.z;
    const int t = threadIdx.x;
    const int r = t >> 2, cp = (t & 3) * 16;
    const ushort_t* src = VB + ((size_t)b * CN + bx * 64 + r) * CD + by * 64 + cp;
    *(uint4*)&tile[r][cp] = *(const uint4*)src;
    *(uint4*)&tile[r][cp + 8] = *(const uint4*)(src + 8);
    __syncthreads();
    ushort_t tmp[16];
#pragma unroll
    for (int i = 0; i < 16; i++) tmp[i] = tile[cp + i][r];
    ushort_t* dst = VT + ((size_t)b * CD + by * 64 + r) * CN + bx * 64 + cp;
    *(uint4*)dst = *(uint4*)tmp;
    *(uint4*)(dst + 8) = *(uint4*)(tmp + 8);
}

// -------------------------------------------------------------------------
extern "C" void kernel_launch(void* const* d_in, const int* in_sizes, int n_in,
                              void* d_out, int out_size, void* d_ws, size_t ws_size,
                              hipStream_t stream) {
    const float* x      = (const float*)d_in[0];
    const float* W_qkv  = (const float*)d_in[1];
    const float* b_qkv  = (const float*)d_in[2];
    const float* W_proj = (const float*)d_in[3];
    const float* b_proj = (const float*)d_in[4];
    const float* W_gp   = (const float*)d_in[5];
    const float* alpha  = (const float*)d_in[6];
    float* out = (float*)d_out;

    const size_t BND    = (size_t)CB * CN * CD;        // 12,582,912 elems
    const size_t SZ_BF  = BND * 2;                     // 25,165,824 B
    const size_t SZ_WPT = (size_t)CD * CD * 2;         // 1,179,648 B
    const size_t SZ_GW  = (size_t)CB * CN * NG * 4;    // 3,211,264 B
    const size_t SZ_GWP = (size_t)CB * CN * 64 * 2;    // 2,097,152 B
    const size_t SZ_Z   = (size_t)CB * NG * CD * 4;    // 1,204,224 B
    const size_t SZ_SP  = (size_t)CB * CN * CN * 2;    // 67,108,864 B (hosts xb+wqt early)
    const size_t need = 6 * SZ_BF + SZ_WPT + SZ_GW + SZ_GWP + SZ_Z + SZ_SP;  // ~226 MB
    if (ws_size < need) {
        ws_fail_marker<<<1, 1, 0, stream>>>(out);
        return;
    }
    char* p = (char*)d_ws;
    ushort_t* qb  = (ushort_t*)p; p += SZ_BF;
    ushort_t* kb  = (ushort_t*)p; p += SZ_BF;
    ushort_t* vb  = (ushort_t*)p; p += SZ_BF;
    ushort_t* vt  = (ushort_t*)p; p += SZ_BF;
    ushort_t* gz  = (ushort_t*)p; p += SZ_BF;
    ushort_t* opb = (ushort_t*)p; p += SZ_BF;
    ushort_t* wpt = (ushort_t*)p; p += SZ_WPT;
    float*    gw  = (float*)p;    p += SZ_GW;
    ushort_t* gwp = (ushort_t*)p; p += SZ_GWP;
    float*    Zb  = (float*)p;    p += SZ_Z;
    ushort_t* sp  = (ushort_t*)p; p += SZ_SP;
    // xb and wqt live inside sp (dead before s_gemm writes it)
    ushort_t* xb  = sp;
    ushort_t* wqt = sp + BND;

    (void)hipMemsetAsync(Zb, 0, SZ_Z, stream);
    cast_bf16<<<dim3((int)(BND / 8 / 256)), 256, 0, stream>>>(x, xb, (int)BND);
    wt_kernel<<<dim3(36, 12), 256, 0, stream>>>(W_qkv, wqt, CD, CDQKV);
    wt_kernel<<<dim3(12, 12), 256, 0, stream>>>(W_proj, wpt, CD, CD);
    mfma_gemm<0><<<dim3(128, 18), 256, 0, stream>>>(xb, wqt, b_qkv, qb, kb, vb, nullptr);
    group_weights<<<dim3(4096), 256, 0, stream>>>(vb, W_gp, gw, gwp);
    z_accum<<<dim3(8, 3, 16), 256, 0, stream>>>(vb, gw, Zb);
    gz_kernel<<<dim3(16, 3, 8), 256, 0, stream>>>(gw, Zb, gz);
    vt_transpose<<<dim3(32, 12, 8), 256, 0, stream>>>(vb, vt);
    s_gemm<<<dim3(16, 16, 8), 256, 0, stream>>>(qb, kb, gwp, sp);
    softmax_rows<<<dim3(4096), 256, 0, stream>>>(sp);
    pv_gemm<<<dim3(16, 6, 8), 256, 0, stream>>>(sp, vt, gz, alpha, opb);
    mfma_gemm<1><<<dim3(128, 6), 256, 0, stream>>>(opb, wpt, b_proj, nullptr, nullptr, nullptr, out);
}

// Round 6
// 364.227 us; speedup vs baseline: 24.1031x; 1.5298x over previous
//
#include <hip/hip_runtime.h>
#include <hip/hip_bf16.h>
#include <math.h>

// Problem constants
#define CB 8        // batch
#define CN 2048     // seq len
#define CD 768      // dim
#define CDQKV 2304  // 3*dim
#define NG 49       // groups

typedef unsigned short ushort_t;
typedef __attribute__((ext_vector_type(8))) short bf16x8;
typedef __attribute__((ext_vector_type(4))) float f32x4;

__device__ __forceinline__ float bf2f(ushort_t u) {
    unsigned int x = ((unsigned int)u) << 16;
    return __builtin_bit_cast(float, x);
}
__device__ __forceinline__ ushort_t f2bf(float f) {
    unsigned int u = __builtin_bit_cast(unsigned int, f);
    u += 0x7fff + ((u >> 16) & 1);   // RNE
    return (ushort_t)(u >> 16);
}
__device__ __forceinline__ ushort_t f2h(float f) {
    _Float16 h = (_Float16)f;
    return __builtin_bit_cast(ushort_t, h);
}
__device__ __forceinline__ float h2f(ushort_t u) {
    return (float)__builtin_bit_cast(_Float16, u);
}
__device__ __forceinline__ float sigmoidf_(float x) { return 1.f / (1.f + __expf(-x)); }

__device__ __forceinline__ void gload_lds16(const ushort_t* g, ushort_t* l) {
    __builtin_amdgcn_global_load_lds((const __attribute__((address_space(1))) void*)g,
                                     (__attribute__((address_space(3))) void*)l, 16, 0, 0);
}

// -------------------------------------------------------------------------
__global__ void ws_fail_marker(float* out) {
    if (threadIdx.x == 0 && blockIdx.x == 0) out[0] = 31337.0f;
}

// -------------------------------------------------------------------------
// cast_x: fp32 -> bf16, 8 elems/thread
// -------------------------------------------------------------------------
__global__ __launch_bounds__(256) void cast_bf16(const float* __restrict__ X,
                                                 ushort_t* __restrict__ XB, int n)
{
    int i = (blockIdx.x * 256 + threadIdx.x) * 8;
    if (i >= n) return;
    float4 a = *(const float4*)(X + i);
    float4 b = *(const float4*)(X + i + 4);
    ushort_t t[8];
    t[0] = f2bf(a.x); t[1] = f2bf(a.y); t[2] = f2bf(a.z); t[3] = f2bf(a.w);
    t[4] = f2bf(b.x); t[5] = f2bf(b.y); t[6] = f2bf(b.z); t[7] = f2bf(b.w);
    *(uint4*)(XB + i) = *(uint4*)t;
}

// -------------------------------------------------------------------------
// wt_kernel: W [rows][cols] fp32 -> WT [cols][rows] bf16 (64x64 LDS tiles)
// -------------------------------------------------------------------------
__global__ __launch_bounds__(256) void wt_kernel(const float* __restrict__ W,
                                                 ushort_t* __restrict__ WT,
                                                 int rows, int cols)
{
    __shared__ ushort_t tile[64][72];
    const int bx = blockIdx.x, by = blockIdx.y;
    const int t = threadIdx.x;
    const int r = t >> 2, cp = (t & 3) * 16;
    const float* src = W + (size_t)(by * 64 + r) * cols + bx * 64 + cp;
    ushort_t tmp[16];
#pragma unroll
    for (int i = 0; i < 16; i += 4) {
        float4 v = *(const float4*)(src + i);
        tmp[i + 0] = f2bf(v.x); tmp[i + 1] = f2bf(v.y);
        tmp[i + 2] = f2bf(v.z); tmp[i + 3] = f2bf(v.w);
    }
    *(uint4*)&tile[r][cp] = *(uint4*)tmp;
    *(uint4*)&tile[r][cp + 8] = *(uint4*)(tmp + 8);
    __syncthreads();
#pragma unroll
    for (int i = 0; i < 16; i++) tmp[i] = tile[cp + i][r];
    ushort_t* dst = WT + (size_t)(bx * 64 + r) * rows + by * 64 + cp;
    *(uint4*)dst = *(uint4*)tmp;
    *(uint4*)(dst + 8) = *(uint4*)(tmp + 8);
}

// -------------------------------------------------------------------------
// wgpt_kernel: W_gp [768][49] fp32 -> WGPT [64][768] bf16, rows 49..63 zero
// -------------------------------------------------------------------------
__global__ __launch_bounds__(256) void wgpt_kernel(const float* __restrict__ Wg,
                                                   ushort_t* __restrict__ WGPT)
{
    int idx = blockIdx.x * 256 + threadIdx.x;   // 64*768 = 49152
    if (idx >= 64 * CD) return;
    int gg = idx / CD, k = idx % CD;
    WGPT[idx] = (gg < NG) ? f2bf(Wg[(size_t)k * NG + gg]) : (ushort_t)0;
}

// -------------------------------------------------------------------------
// Shared GEMM machinery: 128x128 tile, BK=64, 256 thr = 4 waves (2x2 of 64x64),
// double-buffered LDS via global_load_lds w=16, source-preswizzled XOR.
// -------------------------------------------------------------------------
#define GEN_STAGE(dstA_, dstB_, kt_, Abase_, Bbase_, lda_, ldb_) do {          \
    _Pragma("unroll")                                                          \
    for (int _p = 0; _p < 4; _p++) {                                           \
        int _idx = _p * 256 + tid;                                             \
        int _row = _idx >> 3;                                                  \
        int _lsl = (_idx & 7) ^ (_row & 7);                                    \
        gload_lds16((Abase_) + (size_t)_row * (lda_) + (size_t)(kt_) * 64 + _lsl * 8, \
                    (dstA_) + _idx * 8);                                       \
        gload_lds16((Bbase_) + (size_t)_row * (ldb_) + (size_t)(kt_) * 64 + _lsl * 8, \
                    (dstB_) + _idx * 8);                                       \
    } } while (0)

#define G_COMPUTE(srcA_, srcB_) do {                                           \
    _Pragma("unroll")                                                          \
    for (int _ks = 0; _ks < 2; _ks++) {                                        \
        bf16x8 _af[4], _bf[4];                                                 \
        _Pragma("unroll")                                                      \
        for (int _f = 0; _f < 4; _f++) {                                       \
            int _ra = wr * 64 + _f * 16 + c;                                   \
            int _pa = (_ks * 4 + g) ^ (_ra & 7);                               \
            _af[_f] = *(const bf16x8*)((srcA_) + _ra * 64 + _pa * 8);          \
            int _rb = wc * 64 + _f * 16 + c;                                   \
            int _pb = (_ks * 4 + g) ^ (_rb & 7);                               \
            _bf[_f] = *(const bf16x8*)((srcB_) + _rb * 64 + _pb * 8);          \
        }                                                                      \
        _Pragma("unroll")                                                      \
        for (int _mf = 0; _mf < 4; _mf++)                                      \
            _Pragma("unroll")                                                  \
            for (int _nf = 0; _nf < 4; _nf++)                                  \
                acc[_mf * 4 + _nf] = __builtin_amdgcn_mfma_f32_16x16x32_bf16(  \
                    _af[_mf], _bf[_nf], acc[_mf * 4 + _nf], 0, 0, 0);          \
    } } while (0)

// A 128 rows, B 64 rows variant (N=64 GEMMs): wave w owns rows w*32..w*32+31
#define STAGE_A128(dst_, base_, ld_, kt_) do {                                 \
    _Pragma("unroll")                                                          \
    for (int _p = 0; _p < 4; _p++) {                                           \
        int _idx = _p * 256 + tid;                                             \
        int _row = _idx >> 3;                                                  \
        int _lsl = (_idx & 7) ^ (_row & 7);                                    \
        gload_lds16((base_) + (size_t)_row * (ld_) + (size_t)(kt_) * 64 + _lsl * 8, \
                    (dst_) + _idx * 8);                                        \
    } } while (0)

#define STAGE_B64(dst_, base_, ld_, kt_) do {                                  \
    _Pragma("unroll")                                                          \
    for (int _p = 0; _p < 2; _p++) {                                           \
        int _idx = _p * 256 + tid;                                             \
        int _row = _idx >> 3;                                                  \
        int _lsl = (_idx & 7) ^ (_row & 7);                                    \
        gload_lds16((base_) + (size_t)_row * (ld_) + (size_t)(kt_) * 64 + _lsl * 8, \
                    (dst_) + _idx * 8);                                        \
    } } while (0)

#define N64_COMPUTE(srcA_, srcB_) do {                                         \
    _Pragma("unroll")                                                          \
    for (int _ks = 0; _ks < 2; _ks++) {                                        \
        bf16x8 _af[2], _bf[4];                                                 \
        _Pragma("unroll")                                                      \
        for (int _f = 0; _f < 2; _f++) {                                       \
            int _ra = w * 32 + _f * 16 + c;                                    \
            int _pa = (_ks * 4 + g) ^ (_ra & 7);                               \
            _af[_f] = *(const bf16x8*)((srcA_) + _ra * 64 + _pa * 8);          \
        }                                                                      \
        _Pragma("unroll")                                                      \
        for (int _f = 0; _f < 4; _f++) {                                       \
            int _rb = _f * 16 + c;                                             \
            int _pb = (_ks * 4 + g) ^ (_rb & 7);                               \
            _bf[_f] = *(const bf16x8*)((srcB_) + _rb * 64 + _pb * 8);          \
        }                                                                      \
        _Pragma("unroll")                                                      \
        for (int _mf = 0; _mf < 2; _mf++)                                      \
            _Pragma("unroll")                                                  \
            for (int _nf = 0; _nf < 4; _nf++)                                  \
                acc[_mf * 4 + _nf] = __builtin_amdgcn_mfma_f32_16x16x32_bf16(  \
                    _af[_mf], _bf[_nf], acc[_mf * 4 + _nf], 0, 0, 0);          \
    } } while (0)

// -------------------------------------------------------------------------
// mfma_gemm: C = A[M][768] @ B^T[N][768]^T + bias.
// OUTMODE 0: split bf16 q/k/v write.  OUTMODE 1: fp32 OUT write.
// -------------------------------------------------------------------------
template <int OUTMODE>
__global__ __launch_bounds__(256, 2) void mfma_gemm(
    const ushort_t* __restrict__ Ag, const ushort_t* __restrict__ Bg,
    const float* __restrict__ bias,
    ushort_t* __restrict__ Qd, ushort_t* __restrict__ Kd, ushort_t* __restrict__ Vd,
    float* __restrict__ OUT)
{
    __shared__ __align__(16) ushort_t As[2][128 * 64];
    __shared__ __align__(16) ushort_t Bs[2][128 * 64];
    const int tid = threadIdx.x;
    const int lane = tid & 63;
    const int w = tid >> 6;
    const int c = lane & 15, g = lane >> 4;
    const int wr = w >> 1, wc = w & 1;
    const int m0 = blockIdx.x * 128;
    const int n0 = blockIdx.y * 128;
    const ushort_t* Ab = Ag + (size_t)m0 * CD;
    const ushort_t* Bb = Bg + (size_t)n0 * CD;

    f32x4 acc[16];
#pragma unroll
    for (int i = 0; i < 16; i++) acc[i] = (f32x4){0.f, 0.f, 0.f, 0.f};

    GEN_STAGE(As[0], Bs[0], 0, Ab, Bb, CD, CD);
    __syncthreads();
#pragma unroll 1
    for (int kt = 0; kt < 12; kt++) {
        const int cur = kt & 1;
        if (kt < 11) GEN_STAGE(As[cur ^ 1], Bs[cur ^ 1], kt + 1, Ab, Bb, CD, CD);
        G_COMPUTE(As[cur], Bs[cur]);
        __syncthreads();
    }

    if (OUTMODE == 0) {
        const int seg = n0 / CD;
        const int nl0 = n0 % CD;
        ushort_t* dst = (seg == 0) ? Qd : (seg == 1) ? Kd : Vd;
#pragma unroll
        for (int nf = 0; nf < 4; nf++) {
            float bv = bias[n0 + wc * 64 + nf * 16 + c];
            int n = nl0 + wc * 64 + nf * 16 + c;
#pragma unroll
            for (int mf = 0; mf < 4; mf++) {
#pragma unroll
                for (int r = 0; r < 4; r++) {
                    int m = m0 + wr * 64 + mf * 16 + g * 4 + r;
                    dst[(size_t)m * CD + n] = f2bf(acc[mf * 4 + nf][r] + bv);
                }
            }
        }
    } else {
#pragma unroll
        for (int nf = 0; nf < 4; nf++) {
            int n = n0 + wc * 64 + nf * 16 + c;
            float bv = bias[n];
#pragma unroll
            for (int mf = 0; mf < 4; mf++) {
#pragma unroll
                for (int r = 0; r < 4; r++) {
                    int m = m0 + wr * 64 + mf * 16 + g * 4 + r;
                    OUT[(size_t)m * CD + n] = acc[mf * 4 + nf][r] + bv;
                }
            }
        }
    }
}

// -------------------------------------------------------------------------
// gw_gemm: gw = softmax49(gelu_exact(v @ W_gp)) via MFMA.
// A = v [16384][768], B = WGPT [64][768]. Fused epilogue does gelu+softmax.
// Outputs: GWP [row][64] bf16 (padded), GWT [b][64][2048] bf16 (transposed).
// grid 128 blocks x 256 thr.
// -------------------------------------------------------------------------
__global__ __launch_bounds__(256, 2) void gw_gemm(
    const ushort_t* __restrict__ Vb, const ushort_t* __restrict__ WGPT,
    ushort_t* __restrict__ GWP, ushort_t* __restrict__ GWT)
{
    __shared__ __align__(16) ushort_t As[2][128 * 64];
    __shared__ __align__(16) ushort_t Bs[2][64 * 64];
    const int tid = threadIdx.x;
    const int lane = tid & 63;
    const int w = tid >> 6;
    const int c = lane & 15, g = lane >> 4;
    const int row0 = blockIdx.x * 128;
    const ushort_t* Ab = Vb + (size_t)row0 * CD;

    f32x4 acc[8];  // [mf(2)][nf(4)]
#pragma unroll
    for (int i = 0; i < 8; i++) acc[i] = (f32x4){0.f, 0.f, 0.f, 0.f};

    STAGE_A128(As[0], Ab, CD, 0);
    STAGE_B64(Bs[0], WGPT, CD, 0);
    __syncthreads();
#pragma unroll 1
    for (int kt = 0; kt < 12; kt++) {
        const int cur = kt & 1;
        if (kt < 11) {
            STAGE_A128(As[cur ^ 1], Ab, CD, kt + 1);
            STAGE_B64(Bs[cur ^ 1], WGPT, CD, kt + 1);
        }
        N64_COMPUTE(As[cur], Bs[cur]);
        __syncthreads();
    }

    // fused gelu (exact) + softmax over 49 groups.
    // lane holds row = row0 + w*32 + mf*16 + g*4 + rr, col = nf*16 + c.
    float gl[2][4][4];
#pragma unroll
    for (int mf = 0; mf < 2; mf++)
#pragma unroll
        for (int nf = 0; nf < 4; nf++) {
            int col = nf * 16 + c;
#pragma unroll
            for (int rr = 0; rr < 4; rr++) {
                float xx = acc[mf * 4 + nf][rr];
                float ge = 0.5f * xx * (1.f + erff(xx * 0.7071067811865475f));
                gl[mf][nf][rr] = (col < NG) ? ge : -1e30f;
            }
        }
#pragma unroll
    for (int mf = 0; mf < 2; mf++) {
#pragma unroll
        for (int rr = 0; rr < 4; rr++) {
            float m = fmaxf(fmaxf(gl[mf][0][rr], gl[mf][1][rr]),
                            fmaxf(gl[mf][2][rr], gl[mf][3][rr]));
#pragma unroll
            for (int s = 1; s < 16; s <<= 1) m = fmaxf(m, __shfl_xor(m, s, 64));
            float ssum = 0.f;
#pragma unroll
            for (int nf = 0; nf < 4; nf++) {
                int col = nf * 16 + c;
                float e = (col < NG) ? __expf(gl[mf][nf][rr] - m) : 0.f;
                gl[mf][nf][rr] = e;
                ssum += e;
            }
#pragma unroll
            for (int s = 1; s < 16; s <<= 1) ssum += __shfl_xor(ssum, s, 64);
            float inv = 1.f / ssum;
            int row = row0 + w * 32 + mf * 16 + g * 4 + rr;
            int bb = row >> 11, nn = row & 2047;
#pragma unroll
            for (int nf = 0; nf < 4; nf++) {
                int col = nf * 16 + c;
                ushort_t wv = f2bf(gl[mf][nf][rr] * inv);
                GWP[(size_t)row * 64 + col] = wv;
                GWT[((size_t)bb * 64 + col) * CN + nn] = wv;
            }
        }
    }
}

// -------------------------------------------------------------------------
// z_gemm: ZT[b][d][g] = sum_n vt[b][d][n] * gwt[b][g][n]  (bf16 out, fp32 acc)
// A = vt [768][2048], B = gwt [64][2048], K=2048. grid (6, 8).
// -------------------------------------------------------------------------
__global__ __launch_bounds__(256, 2) void z_gemm(
    const ushort_t* __restrict__ VT, const ushort_t* __restrict__ GWT,
    ushort_t* __restrict__ ZT)
{
    __shared__ __align__(16) ushort_t As[2][128 * 64];
    __shared__ __align__(16) ushort_t Bs[2][64 * 64];
    const int tid = threadIdx.x;
    const int lane = tid & 63;
    const int w = tid >> 6;
    const int c = lane & 15, g = lane >> 4;
    const int b = blockIdx.y;
    const int m0 = blockIdx.x * 128;
    const ushort_t* Ab = VT + ((size_t)b * CD + m0) * CN;
    const ushort_t* Bb = GWT + (size_t)b * 64 * CN;

    f32x4 acc[8];
#pragma unroll
    for (int i = 0; i < 8; i++) acc[i] = (f32x4){0.f, 0.f, 0.f, 0.f};

    STAGE_A128(As[0], Ab, CN, 0);
    STAGE_B64(Bs[0], Bb, CN, 0);
    __syncthreads();
#pragma unroll 1
    for (int kt = 0; kt < 32; kt++) {
        const int cur = kt & 1;
        if (kt < 31) {
            STAGE_A128(As[cur ^ 1], Ab, CN, kt + 1);
            STAGE_B64(Bs[cur ^ 1], Bb, CN, kt + 1);
        }
        N64_COMPUTE(As[cur], Bs[cur]);
        __syncthreads();
    }

#pragma unroll
    for (int mf = 0; mf < 2; mf++)
#pragma unroll
        for (int nf = 0; nf < 4; nf++) {
            int col = nf * 16 + c;
#pragma unroll
            for (int rr = 0; rr < 4; rr++) {
                int row = m0 + w * 32 + mf * 16 + g * 4 + rr;
                ZT[((size_t)b * CD + row) * 64 + col] = f2bf(acc[mf * 4 + nf][rr]);
            }
        }
}

// -------------------------------------------------------------------------
// s_gemm: S[b][q][kv] = (q . k) * scale * G, fp16 out.
// G = gwq @ gwk^T via 32 extra MFMAs, operand frags straight from global.
// grid (16 qb, 16 kvb, 8 b)
// -------------------------------------------------------------------------
__global__ __launch_bounds__(256, 2) void s_gemm(
    const ushort_t* __restrict__ Qb, const ushort_t* __restrict__ Kb,
    const ushort_t* __restrict__ GWP, ushort_t* __restrict__ S)
{
    __shared__ __align__(16) ushort_t As[2][128 * 64];
    __shared__ __align__(16) ushort_t Bs[2][128 * 64];
    const int tid = threadIdx.x;
    const int lane = tid & 63;
    const int w = tid >> 6;
    const int c = lane & 15, g = lane >> 4;
    const int wr = w >> 1, wc = w & 1;
    const int b = blockIdx.z;
    const int m0 = blockIdx.x * 128;
    const int n0 = blockIdx.y * 128;
    const ushort_t* Ab = Qb + ((size_t)b * CN + m0) * CD;
    const ushort_t* Bb = Kb + ((size_t)b * CN + n0) * CD;

    f32x4 acc[16], gacc[16];
#pragma unroll
    for (int i = 0; i < 16; i++) {
        acc[i] = (f32x4){0.f, 0.f, 0.f, 0.f};
        gacc[i] = (f32x4){0.f, 0.f, 0.f, 0.f};
    }

    GEN_STAGE(As[0], Bs[0], 0, Ab, Bb, CD, CD);

    // ---- group-affinity G via MFMA; frags loaded from global (L2-hot) ----
    {
        const ushort_t* Gq = GWP + ((size_t)b * CN + m0) * 64;
        const ushort_t* Gk = GWP + ((size_t)b * CN + n0) * 64;
        bf16x8 gqf[2][4], gkf[2][4];
#pragma unroll
        for (int ks = 0; ks < 2; ks++)
#pragma unroll
            for (int f = 0; f < 4; f++) {
                gqf[ks][f] = *(const bf16x8*)(Gq + (size_t)(wr * 64 + f * 16 + c) * 64 + ks * 32 + g * 8);
                gkf[ks][f] = *(const bf16x8*)(Gk + (size_t)(wc * 64 + f * 16 + c) * 64 + ks * 32 + g * 8);
            }
#pragma unroll
        for (int ks = 0; ks < 2; ks++)
#pragma unroll
            for (int mf = 0; mf < 4; mf++)
#pragma unroll
                for (int nf = 0; nf < 4; nf++)
                    gacc[mf * 4 + nf] = __builtin_amdgcn_mfma_f32_16x16x32_bf16(
                        gqf[ks][mf], gkf[ks][nf], gacc[mf * 4 + nf], 0, 0, 0);
    }

    __syncthreads();
#pragma unroll 1
    for (int kt = 0; kt < 12; kt++) {
        const int cur = kt & 1;
        if (kt < 11) GEN_STAGE(As[cur ^ 1], Bs[cur ^ 1], kt + 1, Ab, Bb, CD, CD);
        G_COMPUTE(As[cur], Bs[cur]);
        __syncthreads();
    }

    ushort_t* Sb = S + ((size_t)b * CN + m0) * CN + n0;
    const float scale = 0.03608439182435161f;  // 768^-0.5
#pragma unroll
    for (int nf = 0; nf < 4; nf++) {
        int n = wc * 64 + nf * 16 + c;
#pragma unroll
        for (int mf = 0; mf < 4; mf++) {
#pragma unroll
            for (int r = 0; r < 4; r++) {
                int m = wr * 64 + mf * 16 + g * 4 + r;
                float z = acc[mf * 4 + nf][r] * scale * gacc[mf * 4 + nf][r];
                Sb[(size_t)m * CN + n] = f2h(z);
            }
        }
    }
}

// -------------------------------------------------------------------------
// softmax_rows: in-place row softmax over CN=2048. fp16 in, bf16 out.
// 1 wave per row, 4 rows per block; 32 vals/lane in registers.
// -------------------------------------------------------------------------
__global__ __launch_bounds__(256) void softmax_rows(ushort_t* __restrict__ SP)
{
    const int lane = threadIdx.x & 63;
    const int row = blockIdx.x * 4 + (threadIdx.x >> 6);
    ushort_t* rp = SP + (size_t)row * CN;

    float v[32];
    float mx = -1e30f;
#pragma unroll
    for (int ch = 0; ch < 4; ch++) {
        uint4 u = *(const uint4*)(rp + ch * 512 + lane * 8);
        const unsigned int uu[4] = {u.x, u.y, u.z, u.w};
#pragma unroll
        for (int j = 0; j < 4; j++) {
            float a = h2f((ushort_t)(uu[j] & 0xffff));
            float bq = h2f((ushort_t)(uu[j] >> 16));
            v[ch * 8 + j * 2] = a;
            v[ch * 8 + j * 2 + 1] = bq;
            mx = fmaxf(mx, fmaxf(a, bq));
        }
    }
#pragma unroll
    for (int s = 32; s > 0; s >>= 1) mx = fmaxf(mx, __shfl_xor(mx, s, 64));
    float sum = 0.f;
#pragma unroll
    for (int i = 0; i < 32; i++) {
        v[i] = __expf(v[i] - mx);
        sum += v[i];
    }
#pragma unroll
    for (int s = 32; s > 0; s >>= 1) sum += __shfl_xor(sum, s, 64);
    float inv = 1.f / sum;
#pragma unroll
    for (int ch = 0; ch < 4; ch++) {
        ushort_t t[8];
#pragma unroll
        for (int j = 0; j < 8; j++) t[j] = f2bf(v[ch * 8 + j] * inv);
        *(uint4*)(rp + ch * 512 + lane * 8) = *(uint4*)t;
    }
}

// -------------------------------------------------------------------------
// pv_gemm: O = (1-a) * P @ V + a * (gw @ Z)   (both via MFMA), bf16 out.
// Main: A = P (bf16, lda=CN), B^T = vt[b][d][kv], K=2048 -> 32 k-tiles.
// GZ part: A-frags from GWP [m][64], B-frags from ZT [d][64], K=64 (global).
// grid (16 qb, 6 db, 8 b).
// -------------------------------------------------------------------------
__global__ __launch_bounds__(256, 2) void pv_gemm(
    const ushort_t* __restrict__ P, const ushort_t* __restrict__ VT,
    const ushort_t* __restrict__ GWP, const ushort_t* __restrict__ ZT,
    const float* __restrict__ alpha_p, ushort_t* __restrict__ OP)
{
    __shared__ __align__(16) ushort_t As[2][128 * 64];
    __shared__ __align__(16) ushort_t Bs[2][128 * 64];
    const int tid = threadIdx.x;
    const int lane = tid & 63;
    const int w = tid >> 6;
    const int c = lane & 15, g = lane >> 4;
    const int wr = w >> 1, wc = w & 1;
    const int b = blockIdx.z;
    const int m0 = blockIdx.x * 128;
    const int n0 = blockIdx.y * 128;
    const ushort_t* Ab = P + ((size_t)b * CN + m0) * CN;
    const ushort_t* Bb = VT + ((size_t)b * CD + n0) * CN;

    f32x4 acc[16], zacc[16];
#pragma unroll
    for (int i = 0; i < 16; i++) {
        acc[i] = (f32x4){0.f, 0.f, 0.f, 0.f};
        zacc[i] = (f32x4){0.f, 0.f, 0.f, 0.f};
    }

    GEN_STAGE(As[0], Bs[0], 0, Ab, Bb, CN, CN);

    // ---- gz = gw @ Z via MFMA; frags from global (L2-hot) ----
    {
        const ushort_t* Gq = GWP + ((size_t)b * CN + m0) * 64;
        const ushort_t* Zt = ZT + (size_t)b * CD * 64;
        bf16x8 zaf[2][4], zbf[2][4];
#pragma unroll
        for (int ks = 0; ks < 2; ks++)
#pragma unroll
            for (int f = 0; f < 4; f++) {
                zaf[ks][f] = *(const bf16x8*)(Gq + (size_t)(wr * 64 + f * 16 + c) * 64 + ks * 32 + g * 8);
                zbf[ks][f] = *(const bf16x8*)(Zt + (size_t)(n0 + wc * 64 + f * 16 + c) * 64 + ks * 32 + g * 8);
            }
#pragma unroll
        for (int ks = 0; ks < 2; ks++)
#pragma unroll
            for (int mf = 0; mf < 4; mf++)
#pragma unroll
                for (int nf = 0; nf < 4; nf++)
                    zacc[mf * 4 + nf] = __builtin_amdgcn_mfma_f32_16x16x32_bf16(
                        zaf[ks][mf], zbf[ks][nf], zacc[mf * 4 + nf], 0, 0, 0);
    }

    __syncthreads();
#pragma unroll 1
    for (int kt = 0; kt < 32; kt++) {
        const int cur = kt & 1;
        if (kt < 31) GEN_STAGE(As[cur ^ 1], Bs[cur ^ 1], kt + 1, Ab, Bb, CN, CN);
        G_COMPUTE(As[cur], Bs[cur]);
        __syncthreads();
    }

    const float aa = sigmoidf_(alpha_p[0]);
    ushort_t* OPb = OP + ((size_t)b * CN + m0) * CD;
#pragma unroll
    for (int nf = 0; nf < 4; nf++) {
        int n = n0 + wc * 64 + nf * 16 + c;
#pragma unroll
        for (int mf = 0; mf < 4; mf++) {
#pragma unroll
            for (int r = 0; r < 4; r++) {
                int m = wr * 64 + mf * 16 + g * 4 + r;
                OPb[(size_t)m * CD + n] =
                    f2bf((1.f - aa) * acc[mf * 4 + nf][r] + aa * zacc[mf * 4 + nf][r]);
            }
        }
    }
}

// -------------------------------------------------------------------------
// vt_transpose: vt[b][d][n] = v[b][n][d]  (bf16 transpose), 64x64 tiles
// -------------------------------------------------------------------------
__global__ __launch_bounds__(256) void vt_transpose(const ushort_t* __restrict__ VB,
                                                    ushort_t* __restrict__ VT)
{
    __shared__ ushort_t tile[64][72];
    const int bx = blockIdx.x, by = blockIdx.y, b = blockIdx.z;
    const int t = threadIdx.x;
    const int r = t >> 2, cp = (t & 3) * 16;
    const ushort_t* src = VB + ((size_t)b * CN + bx * 64 + r) * CD + by * 64 + cp;
    *(uint4*)&tile[r][cp] = *(const uint4*)src;
    *(uint4*)&tile[r][cp + 8] = *(const uint4*)(src + 8);
    __syncthreads();
    ushort_t tmp[16];
#pragma unroll
    for (int i = 0; i < 16; i++) tmp[i] = tile[cp + i][r];
    ushort_t* dst = VT + ((size_t)b * CD + by * 64 + r) * CN + bx * 64 + cp;
    *(uint4*)dst = *(uint4*)tmp;
    *(uint4*)(dst + 8) = *(uint4*)(tmp + 8);
}

// -------------------------------------------------------------------------
extern "C" void kernel_launch(void* const* d_in, const int* in_sizes, int n_in,
                              void* d_out, int out_size, void* d_ws, size_t ws_size,
                              hipStream_t stream) {
    const float* x      = (const float*)d_in[0];
    const float* W_qkv  = (const float*)d_in[1];
    const float* b_qkv  = (const float*)d_in[2];
    const float* W_proj = (const float*)d_in[3];
    const float* b_proj = (const float*)d_in[4];
    const float* W_gp   = (const float*)d_in[5];
    const float* alpha  = (const float*)d_in[6];
    float* out = (float*)d_out;

    const size_t BND    = (size_t)CB * CN * CD;        // 12,582,912 elems
    const size_t SZ_BF  = BND * 2;                     // 25,165,824 B
    const size_t SZ_WPT = (size_t)CD * CD * 2;         // 1,179,648 B
    const size_t SZ_GWP = (size_t)CB * CN * 64 * 2;    // 2,097,152 B
    const size_t SZ_GWT = (size_t)CB * 64 * CN * 2;    // 2,097,152 B
    const size_t SZ_ZT  = (size_t)CB * CD * 64 * 2;    // 786,432 B
    const size_t SZ_WGPT= (size_t)64 * CD * 2;         // 98,304 B
    const size_t SZ_SP  = (size_t)CB * CN * CN * 2;    // 67,108,864 B (hosts xb+wqt early)
    const size_t need = 5 * SZ_BF + SZ_WPT + SZ_GWP + SZ_GWT + SZ_ZT + SZ_WGPT + SZ_SP;  // ~199 MB
    if (ws_size < need) {
        ws_fail_marker<<<1, 1, 0, stream>>>(out);
        return;
    }
    char* p = (char*)d_ws;
    ushort_t* qb   = (ushort_t*)p; p += SZ_BF;
    ushort_t* kb   = (ushort_t*)p; p += SZ_BF;
    ushort_t* vb   = (ushort_t*)p; p += SZ_BF;
    ushort_t* vt   = (ushort_t*)p; p += SZ_BF;
    ushort_t* opb  = (ushort_t*)p; p += SZ_BF;
    ushort_t* wpt  = (ushort_t*)p; p += SZ_WPT;
    ushort_t* gwp  = (ushort_t*)p; p += SZ_GWP;
    ushort_t* gwt  = (ushort_t*)p; p += SZ_GWT;
    ushort_t* zt   = (ushort_t*)p; p += SZ_ZT;
    ushort_t* wgpt = (ushort_t*)p; p += SZ_WGPT;
    ushort_t* sp   = (ushort_t*)p; p += SZ_SP;
    // xb and wqt live inside sp (dead before s_gemm writes it)
    ushort_t* xb  = sp;
    ushort_t* wqt = sp + BND;

    cast_bf16<<<dim3((int)(BND / 8 / 256)), 256, 0, stream>>>(x, xb, (int)BND);
    wt_kernel<<<dim3(36, 12), 256, 0, stream>>>(W_qkv, wqt, CD, CDQKV);
    wt_kernel<<<dim3(12, 12), 256, 0, stream>>>(W_proj, wpt, CD, CD);
    wgpt_kernel<<<dim3(192), 256, 0, stream>>>(W_gp, wgpt);
    mfma_gemm<0><<<dim3(128, 18), 256, 0, stream>>>(xb, wqt, b_qkv, qb, kb, vb, nullptr);
    gw_gemm<<<dim3(128), 256, 0, stream>>>(vb, wgpt, gwp, gwt);
    vt_transpose<<<dim3(32, 12, 8), 256, 0, stream>>>(vb, vt);
    z_gemm<<<dim3(6, 8), 256, 0, stream>>>(vt, gwt, zt);
    s_gemm<<<dim3(16, 16, 8), 256, 0, stream>>>(qb, kb, gwp, sp);
    softmax_rows<<<dim3(4096), 256, 0, stream>>>(sp);
    pv_gemm<<<dim3(16, 6, 8), 256, 0, stream>>>(sp, vt, gwp, zt, alpha, opb);
    mfma_gemm<1><<<dim3(128, 6), 256, 0, stream>>>(opb, wpt, b_proj, nullptr, nullptr, nullptr, out);
}

// Round 7
// 360.972 us; speedup vs baseline: 24.3204x; 1.0090x over previous
//
#include <hip/hip_runtime.h>
#include <hip/hip_bf16.h>
#include <math.h>

// Problem constants
#define CB 8        // batch
#define CN 2048     // seq len
#define CD 768      // dim
#define CDQKV 2304  // 3*dim
#define NG 49       // groups
#define SLD 2112    // padded K-row stride for P|a*gw concat (2048 + 64)

typedef unsigned short ushort_t;
typedef __attribute__((ext_vector_type(8))) short bf16x8;
typedef __attribute__((ext_vector_type(4))) float f32x4;

__device__ __forceinline__ float bf2f(ushort_t u) {
    unsigned int x = ((unsigned int)u) << 16;
    return __builtin_bit_cast(float, x);
}
__device__ __forceinline__ ushort_t f2bf(float f) {
    unsigned int u = __builtin_bit_cast(unsigned int, f);
    u += 0x7fff + ((u >> 16) & 1);   // RNE
    return (ushort_t)(u >> 16);
}
__device__ __forceinline__ ushort_t f2h(float f) {
    _Float16 h = (_Float16)f;
    return __builtin_bit_cast(ushort_t, h);
}
__device__ __forceinline__ float h2f(ushort_t u) {
    return (float)__builtin_bit_cast(_Float16, u);
}
__device__ __forceinline__ float sigmoidf_(float x) { return 1.f / (1.f + __expf(-x)); }

__device__ __forceinline__ void gload_lds16(const ushort_t* g, ushort_t* l) {
    __builtin_amdgcn_global_load_lds((const __attribute__((address_space(1))) void*)g,
                                     (__attribute__((address_space(3))) void*)l, 16, 0, 0);
}

// -------------------------------------------------------------------------
__global__ void ws_fail_marker(float* out) {
    if (threadIdx.x == 0 && blockIdx.x == 0) out[0] = 31337.0f;
}

// -------------------------------------------------------------------------
__global__ __launch_bounds__(256) void cast_bf16(const float* __restrict__ X,
                                                 ushort_t* __restrict__ XB, int n)
{
    int i = (blockIdx.x * 256 + threadIdx.x) * 8;
    if (i >= n) return;
    float4 a = *(const float4*)(X + i);
    float4 b = *(const float4*)(X + i + 4);
    ushort_t t[8];
    t[0] = f2bf(a.x); t[1] = f2bf(a.y); t[2] = f2bf(a.z); t[3] = f2bf(a.w);
    t[4] = f2bf(b.x); t[5] = f2bf(b.y); t[6] = f2bf(b.z); t[7] = f2bf(b.w);
    *(uint4*)(XB + i) = *(uint4*)t;
}

// -------------------------------------------------------------------------
__global__ __launch_bounds__(256) void wt_kernel(const float* __restrict__ W,
                                                 ushort_t* __restrict__ WT,
                                                 int rows, int cols)
{
    __shared__ ushort_t tile[64][72];
    const int bx = blockIdx.x, by = blockIdx.y;
    const int t = threadIdx.x;
    const int r = t >> 2, cp = (t & 3) * 16;
    const float* src = W + (size_t)(by * 64 + r) * cols + bx * 64 + cp;
    ushort_t tmp[16];
#pragma unroll
    for (int i = 0; i < 16; i += 4) {
        float4 v = *(const float4*)(src + i);
        tmp[i + 0] = f2bf(v.x); tmp[i + 1] = f2bf(v.y);
        tmp[i + 2] = f2bf(v.z); tmp[i + 3] = f2bf(v.w);
    }
    *(uint4*)&tile[r][cp] = *(uint4*)tmp;
    *(uint4*)&tile[r][cp + 8] = *(uint4*)(tmp + 8);
    __syncthreads();
#pragma unroll
    for (int i = 0; i < 16; i++) tmp[i] = tile[cp + i][r];
    ushort_t* dst = WT + (size_t)(bx * 64 + r) * rows + by * 64 + cp;
    *(uint4*)dst = *(uint4*)tmp;
    *(uint4*)(dst + 8) = *(uint4*)(tmp + 8);
}

// -------------------------------------------------------------------------
__global__ __launch_bounds__(256) void wgpt_kernel(const float* __restrict__ Wg,
                                                   ushort_t* __restrict__ WGPT)
{
    int idx = blockIdx.x * 256 + threadIdx.x;   // 64*768 = 49152
    if (idx >= 64 * CD) return;
    int gg = idx / CD, k = idx % CD;
    WGPT[idx] = (gg < NG) ? f2bf(Wg[(size_t)k * NG + gg]) : (ushort_t)0;
}

// =========================================================================
// gemm256: 256x256 tile, BK=64, 512 thr = 8 waves (2x4), per-wave 128x64.
// Counted-vmcnt pipeline (T4): prefetch distance 2 K-tiles, raw s_barrier,
// never drain vmcnt to 0 in the loop. XOR-swizzled LDS (T2), setprio (T5),
// XCD-aware 1-D grid decode (T1). M is always 16384 (Mb=64 blocks).
// OUTMODE 0: split bf16 q/k/v + bias. 1: fp32 out + bias. 2: bf16 out.
// =========================================================================
#define STAGE256(dstA_, dstB_, kt_) do {                                       \
    _Pragma("unroll")                                                          \
    for (int _p = 0; _p < 4; _p++) {                                           \
        int _idx = _p * 512 + tid;                                             \
        int _row = _idx >> 3;                                                  \
        int _lsl = (_idx & 7) ^ (_row & 7);                                    \
        gload_lds16(Ab + (size_t)_row * LDA + (size_t)(kt_) * 64 + _lsl * 8,   \
                    (dstA_) + _idx * 8);                                       \
    }                                                                          \
    _Pragma("unroll")                                                          \
    for (int _p = 0; _p < 4; _p++) {                                           \
        int _idx = _p * 512 + tid;                                             \
        int _row = _idx >> 3;                                                  \
        int _lsl = (_idx & 7) ^ (_row & 7);                                    \
        gload_lds16(Bb + (size_t)_row * LDB + (size_t)(kt_) * 64 + _lsl * 8,   \
                    (dstB_) + _idx * 8);                                       \
    } } while (0)

template <int OUTMODE, int NK, int LDA, int LDB>
__global__ __launch_bounds__(512, 2) void gemm256(
    const ushort_t* __restrict__ Ag, const ushort_t* __restrict__ Bg,
    const float* __restrict__ bias,
    ushort_t* __restrict__ Qd, ushort_t* __restrict__ Kd, ushort_t* __restrict__ Vd,
    ushort_t* __restrict__ OB, float* __restrict__ OF)
{
    __shared__ __align__(16) ushort_t bufA[2][256 * 64];   // 64 KB
    __shared__ __align__(16) ushort_t bufB[2][256 * 64];   // 64 KB

    const int tid = threadIdx.x;
    const int lane = tid & 63;
    const int w = tid >> 6;
    const int c = lane & 15, g = lane >> 4;
    const int wr = w >> 2, wc = w & 3;          // 2 x 4 wave grid

    // T1: XCD-aware decode of 1-D grid (gridDim.x % 8 == 0 for all uses)
    const int per = gridDim.x >> 3;
    const int idx = (blockIdx.x & 7) * per + (blockIdx.x >> 3);
    const int mb = idx & 63;                     // M/256 = 64 always
    const int nb = idx >> 6;
    const int m0 = mb * 256;
    const int n0 = nb * 256;

    const ushort_t* Ab = Ag + (size_t)m0 * LDA;
    const ushort_t* Bb = (OUTMODE == 2)
        ? Bg + ((size_t)(m0 >> 11) * CD + n0) * LDB   // per-batch V^T panel
        : Bg + (size_t)n0 * LDB;

    f32x4 acc[8][4];
#pragma unroll
    for (int i = 0; i < 8; i++)
#pragma unroll
        for (int j = 0; j < 4; j++) acc[i][j] = (f32x4){0.f, 0.f, 0.f, 0.f};

    STAGE256(bufA[0], bufB[0], 0);
    STAGE256(bufA[1], bufB[1], 1);

#pragma unroll 1
    for (int kt = 0; kt < NK; kt++) {
        const int cur = kt & 1;
        // buf[cur] ready when the 8 loads *after* its stage remain in flight
        asm volatile("s_waitcnt vmcnt(8)" ::: "memory");
        __builtin_amdgcn_s_barrier();

        bf16x8 af[2][8], bf[2][4];
#pragma unroll
        for (int ks = 0; ks < 2; ks++) {
#pragma unroll
            for (int mf = 0; mf < 8; mf++) {
                int ra = wr * 128 + mf * 16 + c;
                int pa = (ks * 4 + g) ^ (ra & 7);
                af[ks][mf] = *(const bf16x8*)(&bufA[cur][0] + ra * 64 + pa * 8);
            }
#pragma unroll
            for (int nf = 0; nf < 4; nf++) {
                int rb = wc * 64 + nf * 16 + c;
                int pb = (ks * 4 + g) ^ (rb & 7);
                bf[ks][nf] = *(const bf16x8*)(&bufB[cur][0] + rb * 64 + pb * 8);
            }
        }
        asm volatile("s_waitcnt lgkmcnt(0)" ::: "memory");   // my reads done
        __builtin_amdgcn_s_barrier();                         // everyone's done
        if (kt + 2 < NK) STAGE256(bufA[cur], bufB[cur], kt + 2);  // fly under MFMA

        __builtin_amdgcn_s_setprio(1);
#pragma unroll
        for (int ks = 0; ks < 2; ks++)
#pragma unroll
            for (int mf = 0; mf < 8; mf++)
#pragma unroll
                for (int nf = 0; nf < 4; nf++)
                    acc[mf][nf] = __builtin_amdgcn_mfma_f32_16x16x32_bf16(
                        af[ks][mf], bf[ks][nf], acc[mf][nf], 0, 0, 0);
        __builtin_amdgcn_s_setprio(0);
    }

    // ---- epilogue ----
    if (OUTMODE == 0) {
        const int seg = n0 / CD;                 // 256 | 768 -> no straddle
        const int nl0 = n0 % CD;
        ushort_t* dst = (seg == 0) ? Qd : (seg == 1) ? Kd : Vd;
#pragma unroll
        for (int nf = 0; nf < 4; nf++) {
            float bv = bias[n0 + wc * 64 + nf * 16 + c];
            int n = nl0 + wc * 64 + nf * 16 + c;
#pragma unroll
            for (int mf = 0; mf < 8; mf++)
#pragma unroll
                for (int r = 0; r < 4; r++) {
                    int m = m0 + wr * 128 + mf * 16 + g * 4 + r;
                    dst[(size_t)m * CD + n] = f2bf(acc[mf][nf][r] + bv);
                }
        }
    } else if (OUTMODE == 1) {
#pragma unroll
        for (int nf = 0; nf < 4; nf++) {
            int n = n0 + wc * 64 + nf * 16 + c;
            float bv = bias[n];
#pragma unroll
            for (int mf = 0; mf < 8; mf++)
#pragma unroll
                for (int r = 0; r < 4; r++) {
                    int m = m0 + wr * 128 + mf * 16 + g * 4 + r;
                    OF[(size_t)m * CD + n] = acc[mf][nf][r] + bv;
                }
        }
    } else {
#pragma unroll
        for (int nf = 0; nf < 4; nf++) {
            int n = n0 + wc * 64 + nf * 16 + c;
#pragma unroll
            for (int mf = 0; mf < 8; mf++)
#pragma unroll
                for (int r = 0; r < 4; r++) {
                    int m = m0 + wr * 128 + mf * 16 + g * 4 + r;
                    OB[(size_t)m * CD + n] = f2bf(acc[mf][nf][r]);
                }
        }
    }
}

// =========================================================================
// 128x128 2-phase machinery (kept for s_gemm / gw_gemm / z_gemm)
// =========================================================================
#define GEN_STAGE(dstA_, dstB_, kt_, Abase_, Bbase_, lda_, ldb_) do {          \
    _Pragma("unroll")                                                          \
    for (int _p = 0; _p < 4; _p++) {                                           \
        int _idx = _p * 256 + tid;                                             \
        int _row = _idx >> 3;                                                  \
        int _lsl = (_idx & 7) ^ (_row & 7);                                    \
        gload_lds16((Abase_) + (size_t)_row * (lda_) + (size_t)(kt_) * 64 + _lsl * 8, \
                    (dstA_) + _idx * 8);                                       \
        gload_lds16((Bbase_) + (size_t)_row * (ldb_) + (size_t)(kt_) * 64 + _lsl * 8, \
                    (dstB_) + _idx * 8);                                       \
    } } while (0)

#define G_COMPUTE(srcA_, srcB_) do {                                           \
    _Pragma("unroll")                                                          \
    for (int _ks = 0; _ks < 2; _ks++) {                                        \
        bf16x8 _af[4], _bf[4];                                                 \
        _Pragma("unroll")                                                      \
        for (int _f = 0; _f < 4; _f++) {                                       \
            int _ra = wr * 64 + _f * 16 + c;                                   \
            int _pa = (_ks * 4 + g) ^ (_ra & 7);                               \
            _af[_f] = *(const bf16x8*)((srcA_) + _ra * 64 + _pa * 8);          \
            int _rb = wc * 64 + _f * 16 + c;                                   \
            int _pb = (_ks * 4 + g) ^ (_rb & 7);                               \
            _bf[_f] = *(const bf16x8*)((srcB_) + _rb * 64 + _pb * 8);          \
        }                                                                      \
        _Pragma("unroll")                                                      \
        for (int _mf = 0; _mf < 4; _mf++)                                      \
            _Pragma("unroll")                                                  \
            for (int _nf = 0; _nf < 4; _nf++)                                  \
                acc[_mf * 4 + _nf] = __builtin_amdgcn_mfma_f32_16x16x32_bf16(  \
                    _af[_mf], _bf[_nf], acc[_mf * 4 + _nf], 0, 0, 0);          \
    } } while (0)

#define STAGE_A128(dst_, base_, ld_, kt_) do {                                 \
    _Pragma("unroll")                                                          \
    for (int _p = 0; _p < 4; _p++) {                                           \
        int _idx = _p * 256 + tid;                                             \
        int _row = _idx >> 3;                                                  \
        int _lsl = (_idx & 7) ^ (_row & 7);                                    \
        gload_lds16((base_) + (size_t)_row * (ld_) + (size_t)(kt_) * 64 + _lsl * 8, \
                    (dst_) + _idx * 8);                                        \
    } } while (0)

#define STAGE_B64(dst_, base_, ld_, kt_) do {                                  \
    _Pragma("unroll")                                                          \
    for (int _p = 0; _p < 2; _p++) {                                           \
        int _idx = _p * 256 + tid;                                             \
        int _row = _idx >> 3;                                                  \
        int _lsl = (_idx & 7) ^ (_row & 7);                                    \
        gload_lds16((base_) + (size_t)_row * (ld_) + (size_t)(kt_) * 64 + _lsl * 8, \
                    (dst_) + _idx * 8);                                        \
    } } while (0)

#define N64_COMPUTE(srcA_, srcB_) do {                                         \
    _Pragma("unroll")                                                          \
    for (int _ks = 0; _ks < 2; _ks++) {                                        \
        bf16x8 _af[2], _bf[4];                                                 \
        _Pragma("unroll")                                                      \
        for (int _f = 0; _f < 2; _f++) {                                       \
            int _ra = w * 32 + _f * 16 + c;                                    \
            int _pa = (_ks * 4 + g) ^ (_ra & 7);                               \
            _af[_f] = *(const bf16x8*)((srcA_) + _ra * 64 + _pa * 8);          \
        }                                                                      \
        _Pragma("unroll")                                                      \
        for (int _f = 0; _f < 4; _f++) {                                       \
            int _rb = _f * 16 + c;                                             \
            int _pb = (_ks * 4 + g) ^ (_rb & 7);                               \
            _bf[_f] = *(const bf16x8*)((srcB_) + _rb * 64 + _pb * 8);          \
        }                                                                      \
        _Pragma("unroll")                                                      \
        for (int _mf = 0; _mf < 2; _mf++)                                      \
            _Pragma("unroll")                                                  \
            for (int _nf = 0; _nf < 4; _nf++)                                  \
                acc[_mf * 4 + _nf] = __builtin_amdgcn_mfma_f32_16x16x32_bf16(  \
                    _af[_mf], _bf[_nf], acc[_mf * 4 + _nf], 0, 0, 0);          \
    } } while (0)

// -------------------------------------------------------------------------
// gw_gemm: gw = softmax49(gelu_exact(v @ W_gp)) via MFMA, fused epilogue.
// -------------------------------------------------------------------------
__global__ __launch_bounds__(256, 2) void gw_gemm(
    const ushort_t* __restrict__ Vb, const ushort_t* __restrict__ WGPT,
    ushort_t* __restrict__ GWP, ushort_t* __restrict__ GWT)
{
    __shared__ __align__(16) ushort_t As[2][128 * 64];
    __shared__ __align__(16) ushort_t Bs[2][64 * 64];
    const int tid = threadIdx.x;
    const int lane = tid & 63;
    const int w = tid >> 6;
    const int c = lane & 15, g = lane >> 4;
    const int row0 = blockIdx.x * 128;
    const ushort_t* Ab = Vb + (size_t)row0 * CD;

    f32x4 acc[8];
#pragma unroll
    for (int i = 0; i < 8; i++) acc[i] = (f32x4){0.f, 0.f, 0.f, 0.f};

    STAGE_A128(As[0], Ab, CD, 0);
    STAGE_B64(Bs[0], WGPT, CD, 0);
    __syncthreads();
#pragma unroll 1
    for (int kt = 0; kt < 12; kt++) {
        const int cur = kt & 1;
        if (kt < 11) {
            STAGE_A128(As[cur ^ 1], Ab, CD, kt + 1);
            STAGE_B64(Bs[cur ^ 1], WGPT, CD, kt + 1);
        }
        N64_COMPUTE(As[cur], Bs[cur]);
        __syncthreads();
    }

    float gl[2][4][4];
#pragma unroll
    for (int mf = 0; mf < 2; mf++)
#pragma unroll
        for (int nf = 0; nf < 4; nf++) {
            int col = nf * 16 + c;
#pragma unroll
            for (int rr = 0; rr < 4; rr++) {
                float xx = acc[mf * 4 + nf][rr];
                float ge = 0.5f * xx * (1.f + erff(xx * 0.7071067811865475f));
                gl[mf][nf][rr] = (col < NG) ? ge : -1e30f;
            }
        }
#pragma unroll
    for (int mf = 0; mf < 2; mf++) {
#pragma unroll
        for (int rr = 0; rr < 4; rr++) {
            float m = fmaxf(fmaxf(gl[mf][0][rr], gl[mf][1][rr]),
                            fmaxf(gl[mf][2][rr], gl[mf][3][rr]));
#pragma unroll
            for (int s = 1; s < 16; s <<= 1) m = fmaxf(m, __shfl_xor(m, s, 64));
            float ssum = 0.f;
#pragma unroll
            for (int nf = 0; nf < 4; nf++) {
                int col = nf * 16 + c;
                float e = (col < NG) ? __expf(gl[mf][nf][rr] - m) : 0.f;
                gl[mf][nf][rr] = e;
                ssum += e;
            }
#pragma unroll
            for (int s = 1; s < 16; s <<= 1) ssum += __shfl_xor(ssum, s, 64);
            float inv = 1.f / ssum;
            int row = row0 + w * 32 + mf * 16 + g * 4 + rr;
            int bb = row >> 11, nn = row & 2047;
#pragma unroll
            for (int nf = 0; nf < 4; nf++) {
                int col = nf * 16 + c;
                ushort_t wv = f2bf(gl[mf][nf][rr] * inv);
                GWP[(size_t)row * 64 + col] = wv;
                GWT[((size_t)bb * 64 + col) * CN + nn] = wv;
            }
        }
    }
}

// -------------------------------------------------------------------------
// z_gemm: Z^T[b][d][g] = sum_n vt[b][d][n]*gwt[b][g][n]; writes into the
// TAIL columns (2048..2111) of the stride-2112 vt buffer.
// -------------------------------------------------------------------------
__global__ __launch_bounds__(256, 2) void z_gemm(
    ushort_t* __restrict__ VTt, const ushort_t* __restrict__ GWT)
{
    __shared__ __align__(16) ushort_t As[2][128 * 64];
    __shared__ __align__(16) ushort_t Bs[2][64 * 64];
    const int tid = threadIdx.x;
    const int lane = tid & 63;
    const int w = tid >> 6;
    const int c = lane & 15, g = lane >> 4;
    const int b = blockIdx.y;
    const int m0 = blockIdx.x * 128;
    const ushort_t* Ab = VTt + ((size_t)b * CD + m0) * SLD;
    const ushort_t* Bb = GWT + (size_t)b * 64 * CN;

    f32x4 acc[8];
#pragma unroll
    for (int i = 0; i < 8; i++) acc[i] = (f32x4){0.f, 0.f, 0.f, 0.f};

    STAGE_A128(As[0], Ab, SLD, 0);
    STAGE_B64(Bs[0], Bb, CN, 0);
    __syncthreads();
#pragma unroll 1
    for (int kt = 0; kt < 32; kt++) {
        const int cur = kt & 1;
        if (kt < 31) {
            STAGE_A128(As[cur ^ 1], Ab, SLD, kt + 1);
            STAGE_B64(Bs[cur ^ 1], Bb, CN, kt + 1);
        }
        N64_COMPUTE(As[cur], Bs[cur]);
        __syncthreads();
    }

#pragma unroll
    for (int mf = 0; mf < 2; mf++)
#pragma unroll
        for (int nf = 0; nf < 4; nf++) {
            int col = nf * 16 + c;
#pragma unroll
            for (int rr = 0; rr < 4; rr++) {
                int row = m0 + w * 32 + mf * 16 + g * 4 + rr;
                VTt[((size_t)b * CD + row) * SLD + 2048 + col] = f2bf(acc[mf * 4 + nf][rr]);
            }
        }
}

// -------------------------------------------------------------------------
// s_gemm: S = (q.k)*scale*G, fp16 out at row-stride SLD. (128^2, 2-phase)
// -------------------------------------------------------------------------
__global__ __launch_bounds__(256, 2) void s_gemm(
    const ushort_t* __restrict__ Qb, const ushort_t* __restrict__ Kb,
    const ushort_t* __restrict__ GWP, ushort_t* __restrict__ S)
{
    __shared__ __align__(16) ushort_t As[2][128 * 64];
    __shared__ __align__(16) ushort_t Bs[2][128 * 64];
    const int tid = threadIdx.x;
    const int lane = tid & 63;
    const int w = tid >> 6;
    const int c = lane & 15, g = lane >> 4;
    const int wr = w >> 1, wc = w & 1;
    const int b = blockIdx.z;
    const int m0 = blockIdx.x * 128;
    const int n0 = blockIdx.y * 128;
    const ushort_t* Ab = Qb + ((size_t)b * CN + m0) * CD;
    const ushort_t* Bb = Kb + ((size_t)b * CN + n0) * CD;

    f32x4 acc[16], gacc[16];
#pragma unroll
    for (int i = 0; i < 16; i++) {
        acc[i] = (f32x4){0.f, 0.f, 0.f, 0.f};
        gacc[i] = (f32x4){0.f, 0.f, 0.f, 0.f};
    }

    GEN_STAGE(As[0], Bs[0], 0, Ab, Bb, CD, CD);

    {
        const ushort_t* Gq = GWP + ((size_t)b * CN + m0) * 64;
        const ushort_t* Gk = GWP + ((size_t)b * CN + n0) * 64;
        bf16x8 gqf[2][4], gkf[2][4];
#pragma unroll
        for (int ks = 0; ks < 2; ks++)
#pragma unroll
            for (int f = 0; f < 4; f++) {
                gqf[ks][f] = *(const bf16x8*)(Gq + (size_t)(wr * 64 + f * 16 + c) * 64 + ks * 32 + g * 8);
                gkf[ks][f] = *(const bf16x8*)(Gk + (size_t)(wc * 64 + f * 16 + c) * 64 + ks * 32 + g * 8);
            }
#pragma unroll
        for (int ks = 0; ks < 2; ks++)
#pragma unroll
            for (int mf = 0; mf < 4; mf++)
#pragma unroll
                for (int nf = 0; nf < 4; nf++)
                    gacc[mf * 4 + nf] = __builtin_amdgcn_mfma_f32_16x16x32_bf16(
                        gqf[ks][mf], gkf[ks][nf], gacc[mf * 4 + nf], 0, 0, 0);
    }

    __syncthreads();
#pragma unroll 1
    for (int kt = 0; kt < 12; kt++) {
        const int cur = kt & 1;
        if (kt < 11) GEN_STAGE(As[cur ^ 1], Bs[cur ^ 1], kt + 1, Ab, Bb, CD, CD);
        G_COMPUTE(As[cur], Bs[cur]);
        __syncthreads();
    }

    ushort_t* Sb = S + ((size_t)b * CN + m0) * SLD + n0;
    const float scale = 0.03608439182435161f;  // 768^-0.5
#pragma unroll
    for (int nf = 0; nf < 4; nf++) {
        int n = wc * 64 + nf * 16 + c;
#pragma unroll
        for (int mf = 0; mf < 4; mf++) {
#pragma unroll
            for (int r = 0; r < 4; r++) {
                int m = wr * 64 + mf * 16 + g * 4 + r;
                float z = acc[mf * 4 + nf][r] * scale * gacc[mf * 4 + nf][r];
                Sb[(size_t)m * SLD + n] = f2h(z);
            }
        }
    }
}

// -------------------------------------------------------------------------
// softmax_rows: row softmax over cols 0..2047 (stride SLD), fp16 in,
// bf16 out scaled by (1-a); writes tail cols 2048..2111 = a * gwp[row].
// -------------------------------------------------------------------------
__global__ __launch_bounds__(256) void softmax_rows(ushort_t* __restrict__ SP,
                                                    const ushort_t* __restrict__ GWP,
                                                    const float* __restrict__ alpha_p)
{
    const int lane = threadIdx.x & 63;
    const int row = blockIdx.x * 4 + (threadIdx.x >> 6);
    ushort_t* rp = SP + (size_t)row * SLD;

    float v[32];
    float mx = -1e30f;
#pragma unroll
    for (int ch = 0; ch < 4; ch++) {
        uint4 u = *(const uint4*)(rp + ch * 512 + lane * 8);
        const unsigned int uu[4] = {u.x, u.y, u.z, u.w};
#pragma unroll
        for (int j = 0; j < 4; j++) {
            float a = h2f((ushort_t)(uu[j] & 0xffff));
            float bq = h2f((ushort_t)(uu[j] >> 16));
            v[ch * 8 + j * 2] = a;
            v[ch * 8 + j * 2 + 1] = bq;
            mx = fmaxf(mx, fmaxf(a, bq));
        }
    }
#pragma unroll
    for (int s = 32; s > 0; s >>= 1) mx = fmaxf(mx, __shfl_xor(mx, s, 64));
    float sum = 0.f;
#pragma unroll
    for (int i = 0; i < 32; i++) {
        v[i] = __expf(v[i] - mx);
        sum += v[i];
    }
#pragma unroll
    for (int s = 32; s > 0; s >>= 1) sum += __shfl_xor(sum, s, 64);
    const float aa = sigmoidf_(alpha_p[0]);
    float sc = (1.f - aa) / sum;
#pragma unroll
    for (int ch = 0; ch < 4; ch++) {
        ushort_t t[8];
#pragma unroll
        for (int j = 0; j < 8; j++) t[j] = f2bf(v[ch * 8 + j] * sc);
        *(uint4*)(rp + ch * 512 + lane * 8) = *(uint4*)t;
    }
    if (lane < 8) {   // tail: a * gwp[row][0..63]
        const ushort_t* gp = GWP + (size_t)row * 64 + lane * 8;
        ushort_t t[8];
#pragma unroll
        for (int j = 0; j < 8; j++) t[j] = f2bf(aa * bf2f(gp[j]));
        *(uint4*)(rp + 2048 + lane * 8) = *(uint4*)t;
    }
}

// -------------------------------------------------------------------------
// vt_transpose: vt[b][d][n] = v[b][n][d] into stride-SLD buffer
// -------------------------------------------------------------------------
__global__ __launch_bounds__(256) void vt_transpose(const ushort_t* __restrict__ VB,
                                                    ushort_t* __restrict__ VTt)
{
    __shared__ ushort_t tile[64][72];
    const int bx = blockIdx.x, by = blockIdx.y, b = blockIdx.z;
    const int t = threadIdx.x;
    const int r = t >> 2, cp = (t & 3) * 16;
    const ushort_t* src = VB + ((size_t)b * CN + bx * 64 + r) * CD + by * 64 + cp;
    *(uint4*)&tile[r][cp] = *(const uint4*)src;
    *(uint4*)&tile[r][cp + 8] = *(const uint4*)(src + 8);
    __syncthreads();
    ushort_t tmp[16];
#pragma unroll
    for (int i = 0; i < 16; i++) tmp[i] = tile[cp + i][r];
    ushort_t* dst = VTt + ((size_t)b * CD + by * 64 + r) * SLD + bx * 64 + cp;
    *(uint4*)dst = *(uint4*)tmp;
    *(uint4*)(dst + 8) = *(uint4*)(tmp + 8);
}

// -------------------------------------------------------------------------
extern "C" void kernel_launch(void* const* d_in, const int* in_sizes, int n_in,
                              void* d_out, int out_size, void* d_ws, size_t ws_size,
                              hipStream_t stream) {
    const float* x      = (const float*)d_in[0];
    const float* W_qkv  = (const float*)d_in[1];
    const float* b_qkv  = (const float*)d_in[2];
    const float* W_proj = (const float*)d_in[3];
    const float* b_proj = (const float*)d_in[4];
    const float* W_gp   = (const float*)d_in[5];
    const float* alpha  = (const float*)d_in[6];
    float* out = (float*)d_out;

    const size_t BND    = (size_t)CB * CN * CD;        // 12,582,912 elems
    const size_t SZ_BF  = BND * 2;                     // 25,165,824 B
    const size_t SZ_VT  = (size_t)CB * CD * SLD * 2;   // 25,952,256 B
    const size_t SZ_WPT = (size_t)CD * CD * 2;         // 1,179,648 B
    const size_t SZ_GWP = (size_t)CB * CN * 64 * 2;    // 2,097,152 B
    const size_t SZ_GWT = (size_t)CB * 64 * CN * 2;    // 2,097,152 B
    const size_t SZ_WGPT= (size_t)64 * CD * 2;         // 98,304 B
    const size_t SZ_SP  = (size_t)CB * CN * SLD * 2;   // 69,206,016 B
    const size_t need = 4 * SZ_BF + SZ_VT + SZ_WPT + SZ_GWP + SZ_GWT + SZ_WGPT + SZ_SP;  // ~201 MB
    if (ws_size < need) {
        ws_fail_marker<<<1, 1, 0, stream>>>(out);
        return;
    }
    char* p = (char*)d_ws;
    ushort_t* qb   = (ushort_t*)p; p += SZ_BF;
    ushort_t* kb   = (ushort_t*)p; p += SZ_BF;
    ushort_t* vb   = (ushort_t*)p; p += SZ_BF;
    ushort_t* opb  = (ushort_t*)p; p += SZ_BF;
    ushort_t* vtb  = (ushort_t*)p; p += SZ_VT;
    ushort_t* wpt  = (ushort_t*)p; p += SZ_WPT;
    ushort_t* gwp  = (ushort_t*)p; p += SZ_GWP;
    ushort_t* gwt  = (ushort_t*)p; p += SZ_GWT;
    ushort_t* wgpt = (ushort_t*)p; p += SZ_WGPT;
    ushort_t* sp   = (ushort_t*)p; p += SZ_SP;
    // xb and wqt live inside sp (dead before s_gemm writes it)
    ushort_t* xb  = sp;
    ushort_t* wqt = sp + BND;

    cast_bf16<<<dim3((int)(BND / 8 / 256)), 256, 0, stream>>>(x, xb, (int)BND);
    wt_kernel<<<dim3(36, 12), 256, 0, stream>>>(W_qkv, wqt, CD, CDQKV);
    wt_kernel<<<dim3(12, 12), 256, 0, stream>>>(W_proj, wpt, CD, CD);
    wgpt_kernel<<<dim3(192), 256, 0, stream>>>(W_gp, wgpt);
    // qkv: M=16384, N=2304, K=768
    gemm256<0, 12, CD, CD><<<dim3(576), 512, 0, stream>>>(
        xb, wqt, b_qkv, qb, kb, vb, nullptr, nullptr);
    gw_gemm<<<dim3(128), 256, 0, stream>>>(vb, wgpt, gwp, gwt);
    vt_transpose<<<dim3(32, 12, 8), 256, 0, stream>>>(vb, vtb);
    z_gemm<<<dim3(6, 8), 256, 0, stream>>>(vtb, gwt);
    s_gemm<<<dim3(16, 16, 8), 256, 0, stream>>>(qb, kb, gwp, sp);
    softmax_rows<<<dim3(4096), 256, 0, stream>>>(sp, gwp, alpha);
    // pv: O = P' @ B'^T with K = 2112 (P|a*gw concat), per-batch B panel
    gemm256<2, 33, SLD, SLD><<<dim3(192), 512, 0, stream>>>(
        sp, vtb, nullptr, nullptr, nullptr, nullptr, opb, nullptr);
    // proj: fp32 out + bias
    gemm256<1, 12, CD, CD><<<dim3(192), 512, 0, stream>>>(
        opb, wpt, b_proj, nullptr, nullptr, nullptr, nullptr, out);
}